// Round 3
// baseline (1747.954 us; speedup 1.0000x reference)
//
#include <hip/hip_runtime.h>
#include <math.h>

// ---------------------------------------------------------------------------
// ViT forward, f32. B=1024, D=1024, H=16, DH=64, S=50, OUT=1000.
// Pipeline: PE table -> [per B-chunk: embed(+LN1 stats) -> fused attention]
//           -> residual+LN2 (row 0 only) -> MLP GEMM -> head GEMM -> softmax
// Only tok[:,0] feeds the head, so MLP/head run on (B,1024) not (B*50,1024).
// ---------------------------------------------------------------------------

#define EPS 1e-5f

__device__ __forceinline__ float dot4(float4 a, float4 b, float acc) {
    acc = fmaf(a.x, b.x, acc);
    acc = fmaf(a.y, b.y, acc);
    acc = fmaf(a.z, b.z, acc);
    return fmaf(a.w, b.w, acc);
}

__device__ __forceinline__ float warp_sum64(float v) {
    #pragma unroll
    for (int off = 32; off >= 1; off >>= 1) v += __shfl_xor(v, off, 64);
    return v;
}
__device__ __forceinline__ float warp_max64(float v) {
    #pragma unroll
    for (int off = 32; off >= 1; off >>= 1) v = fmaxf(v, __shfl_xor(v, off, 64));
    return v;
}

__device__ __forceinline__ float block_sum(float v, float* red) {
    v = warp_sum64(v);
    int lane = threadIdx.x & 63, w = threadIdx.x >> 6;
    if (lane == 0) red[w] = v;
    __syncthreads();
    int nw = blockDim.x >> 6;
    if (w == 0) {
        float x = (lane < nw) ? red[lane] : 0.f;
        x = warp_sum64(x);
        if (lane == 0) red[0] = x;
    }
    __syncthreads();
    float r = red[0];
    __syncthreads();
    return r;
}

__device__ __forceinline__ float block_max(float v, float* red) {
    v = warp_max64(v);
    int lane = threadIdx.x & 63, w = threadIdx.x >> 6;
    if (lane == 0) red[w] = v;
    __syncthreads();
    int nw = blockDim.x >> 6;
    if (w == 0) {
        float x = (lane < nw) ? red[lane] : -INFINITY;
        x = warp_max64(x);
        if (lane == 0) red[0] = x;
    }
    __syncthreads();
    float r = red[0];
    __syncthreads();
    return r;
}

// ---------------------------------------------------------------------------
// PE table: pe[s,d]; even d: sin(s/10000^(d/1024)), odd d: cos(s/10000^((d-1)/1024))
// ---------------------------------------------------------------------------
__global__ __launch_bounds__(256) void k_pe(float* __restrict__ pe) {
    int s = blockIdx.x;
    for (int d = threadIdx.x; d < 1024; d += 256) {
        int di = d & ~1;
        float freq = expf(-((float)di * (1.0f / 1024.f)) * 9.210340371976184f); // ln(10000)
        float arg = (float)s * freq;
        pe[s * 1024 + d] = (d & 1) ? cosf(arg) : sinf(arg);
    }
}

// ---------------------------------------------------------------------------
// Embed: one block per (bc, s) row of the chunk. Patchify + Wp dot + cls + PE,
// then LN1 stats (mu, rstd) for the row. Writes tokc, mu_c, rs_c; row 0 also
// saved to persistent tok0.
// ---------------------------------------------------------------------------
__global__ __launch_bounds__(256) void k_embed(
    const float* __restrict__ x, const float* __restrict__ cls,
    const float* __restrict__ Wp, const float* __restrict__ pe,
    float* __restrict__ tokc, float* __restrict__ mu_c, float* __restrict__ rs_c,
    float* __restrict__ tok0, int b0)
{
    int r = blockIdx.x;           // bc*50 + s
    int bc = r / 50, s = r % 50;
    int b = b0 + bc, tid = threadIdx.x;
    __shared__ __align__(16) float pv[16];
    __shared__ float red[8];

    float t[4];
    if (s == 0) {
        #pragma unroll
        for (int i = 0; i < 4; ++i) {
            int d = tid + (i << 8);
            t[i] = cls[d] + pe[d];
        }
    } else {
        int p = s - 1, pr = p / 7, pc = p % 7;
        if (tid < 16)
            pv[tid] = x[(size_t)b * 784 + (pr * 4 + (tid >> 2)) * 28 + pc * 4 + (tid & 3)];
        __syncthreads();
        float4 p0 = *(const float4*)&pv[0];
        float4 p1 = *(const float4*)&pv[4];
        float4 p2 = *(const float4*)&pv[8];
        float4 p3 = *(const float4*)&pv[12];
        #pragma unroll
        for (int i = 0; i < 4; ++i) {
            int d = tid + (i << 8);
            const float4* w4 = (const float4*)(Wp + (size_t)d * 16);
            float acc = 0.f;
            acc = dot4(w4[0], p0, acc);
            acc = dot4(w4[1], p1, acc);
            acc = dot4(w4[2], p2, acc);
            acc = dot4(w4[3], p3, acc);
            t[i] = acc + pe[s * 1024 + d];
        }
    }

    float sum = t[0] + t[1] + t[2] + t[3];
    sum = block_sum(sum, red);
    float mu = sum * (1.f / 1024.f);
    float d2 = 0.f;
    #pragma unroll
    for (int i = 0; i < 4; ++i) { float dv = t[i] - mu; d2 = fmaf(dv, dv, d2); }
    float var = block_sum(d2, red) * (1.f / 1024.f);
    float rstd = rsqrtf(var + EPS);
    if (tid == 0) { mu_c[r] = mu; rs_c[r] = rstd; }

    #pragma unroll
    for (int i = 0; i < 4; ++i)
        tokc[(size_t)r * 1024 + tid + (i << 8)] = t[i];
    if (s == 0) {
        #pragma unroll
        for (int i = 0; i < 4; ++i)
            tok0[(size_t)b * 1024 + tid + (i << 8)] = t[i];
    }
}

// ---------------------------------------------------------------------------
// Fused attention for the class token. One block per (h, bc).
// LN1(slice) -> K,V (LDS-staged weights, 4s x 4e register tiles) -> q0 ->
// softmax over 50 -> A0[b, h*64+e].
// Rows padded to 68 floats (272B, 16B-aligned) to break bank conflicts.
// ---------------------------------------------------------------------------
__device__ __forceinline__ void kv_compute(const float* n_s, const float* w_s,
                                           const float* bias, float* kv_s, int tid)
{
    int m = tid & 15, sg = tid >> 4;
    if (sg >= 13) return;                    // 13*16=208 workers cover 50x64
    int s0 = sg * 4;
    int ns = min(4, 50 - s0);
    float acc[4][4];
    #pragma unroll
    for (int si = 0; si < 4; ++si)
        #pragma unroll
        for (int ri = 0; ri < 4; ++ri)
            acc[si][ri] = bias[m + (ri << 4)];
    #pragma unroll
    for (int d4 = 0; d4 < 16; ++d4) {
        float4 nv[4], wv[4];
        #pragma unroll
        for (int si = 0; si < 4; ++si) {
            int s = (si < ns) ? (s0 + si) : s0;   // clamp, result discarded
            nv[si] = *(const float4*)(n_s + s * 68 + (d4 << 2));
        }
        #pragma unroll
        for (int ri = 0; ri < 4; ++ri)
            wv[ri] = *(const float4*)(w_s + (m + (ri << 4)) * 68 + (d4 << 2));
        #pragma unroll
        for (int si = 0; si < 4; ++si)
            #pragma unroll
            for (int ri = 0; ri < 4; ++ri)
                acc[si][ri] = dot4(nv[si], wv[ri], acc[si][ri]);
    }
    #pragma unroll
    for (int si = 0; si < 4; ++si)
        if (si < ns)
            #pragma unroll
            for (int ri = 0; ri < 4; ++ri)
                kv_s[(s0 + si) * 68 + m + (ri << 4)] = acc[si][ri];
}

__global__ __launch_bounds__(256) void k_attn(
    const float* __restrict__ tokc, const float* __restrict__ mu_c,
    const float* __restrict__ rs_c,
    const float* __restrict__ ln1w, const float* __restrict__ ln1b,
    const float* __restrict__ Wq, const float* __restrict__ bq,
    const float* __restrict__ Wk, const float* __restrict__ bk,
    const float* __restrict__ Wv, const float* __restrict__ bv,
    float* __restrict__ A0, int b0)
{
    __shared__ __align__(16) float n_s[50 * 68];
    __shared__ __align__(16) float w_s[64 * 68];
    __shared__ __align__(16) float kv_s[50 * 68];
    __shared__ __align__(16) float q0s[64];
    __shared__ float p_s[52];

    int h = blockIdx.x, bc = blockIdx.y;
    int tid = threadIdx.x;

    // phase 1: LN1 slice into n_s, stage Wk
    for (int idx = tid; idx < 50 * 64; idx += 256) {
        int s = idx >> 6, e = idx & 63, d = (h << 6) + e;
        int row = bc * 50 + s;
        float t = tokc[(size_t)row * 1024 + d];
        n_s[s * 68 + e] = (t - mu_c[row]) * rs_c[row] * ln1w[d] + ln1b[d];
    }
    for (int idx = tid; idx < 64 * 64; idx += 256) {
        int e = idx >> 6, dd = idx & 63;
        w_s[e * 68 + dd] = Wk[((size_t)h << 12) + idx];
    }
    __syncthreads();

    // q0 (wave 0, weights straight from L2) — other waves proceed to K
    if (tid < 64) {
        int e = tid;
        float acc = bq[(h << 6) + e];
        const float4* wq4 = (const float4*)(Wq + ((size_t)h << 12) + (e << 6));
        const float4* n04 = (const float4*)n_s;   // row 0
        #pragma unroll
        for (int j = 0; j < 16; ++j)
            acc = dot4(wq4[j], n04[j], acc);
        q0s[e] = acc;
    }
    // K = n @ Wk^T + bk
    kv_compute(n_s, w_s, bk + (h << 6), kv_s, tid);
    __syncthreads();

    // scores + softmax over 50 (wave 0); scale = sqrt(1024) = 32 (multiplied!)
    if (tid < 64) {
        int s = tid;
        float sc = -INFINITY;
        if (s < 50) {
            float acc = 0.f;
            const float4* q4 = (const float4*)q0s;
            const float4* k4 = (const float4*)(kv_s + s * 68);
            #pragma unroll
            for (int j = 0; j < 16; ++j)
                acc = dot4(q4[j], k4[j], acc);
            sc = acc * 32.0f;
        }
        float mx = warp_max64(sc);
        float ex = (s < 50) ? expf(sc - mx) : 0.f;
        float sm = warp_sum64(ex);
        if (s < 50) p_s[s] = ex / sm;
    }
    __syncthreads();

    // stage Wv over Wk's buffer
    for (int idx = tid; idx < 64 * 64; idx += 256) {
        int e = idx >> 6, dd = idx & 63;
        w_s[e * 68 + dd] = Wv[((size_t)h << 12) + idx];
    }
    __syncthreads();

    // V = n @ Wv^T + bv (overwrites K — no longer needed)
    kv_compute(n_s, w_s, bv + (h << 6), kv_s, tid);
    __syncthreads();

    // A0[e] = sum_s p[s] * v[s,e]
    if (tid < 64) {
        int e = tid;
        float acc = 0.f;
        #pragma unroll
        for (int s = 0; s < 50; ++s)
            acc = fmaf(p_s[s], kv_s[s * 68 + e], acc);
        A0[(size_t)(b0 + bc) * 1024 + (h << 6) + e] = acc;
    }
}

// ---------------------------------------------------------------------------
// C1: tok0 += A0 (attention residual, row 0); LN2 -> n2. One block per b.
// ---------------------------------------------------------------------------
__global__ __launch_bounds__(256) void k_c1(
    float* __restrict__ tok0, const float* __restrict__ A0,
    const float* __restrict__ w2, const float* __restrict__ b2,
    float* __restrict__ n2)
{
    int b = blockIdx.x, tid = threadIdx.x;
    __shared__ float red[8];
    float t[4];
    #pragma unroll
    for (int i = 0; i < 4; ++i) {
        int d = tid + (i << 8);
        t[i] = tok0[(size_t)b * 1024 + d] + A0[(size_t)b * 1024 + d];
    }
    float sum = t[0] + t[1] + t[2] + t[3];
    sum = block_sum(sum, red);
    float mu = sum * (1.f / 1024.f);
    float d2 = 0.f;
    #pragma unroll
    for (int i = 0; i < 4; ++i) { float dv = t[i] - mu; d2 = fmaf(dv, dv, d2); }
    float var = block_sum(d2, red) * (1.f / 1024.f);
    float rstd = rsqrtf(var + EPS);
    #pragma unroll
    for (int i = 0; i < 4; ++i) {
        int d = tid + (i << 8);
        tok0[(size_t)b * 1024 + d] = t[i];
        n2[(size_t)b * 1024 + d] = (t[i] - mu) * rstd * w2[d] + b2[d];
    }
}

// ---------------------------------------------------------------------------
// Tiled f32 GEMM: C[r,c] = (res? res[r,c] : 0) + bias[c] + sum_k A[r,k]*Bw[c,k]
// A: M x K row-major. Bw: N x K row-major (dot of two rows). M=1024 fixed.
// BM=BN=64, BK=32, 256 threads, 4x4 microtile via float4 LDS reads.
// ---------------------------------------------------------------------------
__global__ __launch_bounds__(256) void k_gemm(
    const float* __restrict__ A, const float* __restrict__ Bw,
    const float* __restrict__ bias, const float* __restrict__ res,
    float* __restrict__ C, int N, int K)
{
    __shared__ __align__(16) float As[32 * 68];
    __shared__ __align__(16) float Bs[32 * 68];
    int n0 = blockIdx.x * 64, m0 = blockIdx.y * 64;
    int tid = threadIdx.x;
    int mt = (tid & 15) * 4, nt = (tid >> 4) * 4;
    float acc[4][4] = {{0.f}};

    for (int k0 = 0; k0 < K; k0 += 32) {
        for (int idx = tid; idx < 64 * 32; idx += 256) {
            int kk = idx & 31, m = idx >> 5;
            As[kk * 68 + m] = A[(size_t)(m0 + m) * K + k0 + kk];
            float bvv = (n0 + m < N) ? Bw[(size_t)(n0 + m) * K + k0 + kk] : 0.f;
            Bs[kk * 68 + m] = bvv;
        }
        __syncthreads();
        #pragma unroll 8
        for (int kk = 0; kk < 32; ++kk) {
            float4 av = *(const float4*)&As[kk * 68 + mt];
            float4 bv = *(const float4*)&Bs[kk * 68 + nt];
            acc[0][0] = fmaf(av.x, bv.x, acc[0][0]);
            acc[0][1] = fmaf(av.x, bv.y, acc[0][1]);
            acc[0][2] = fmaf(av.x, bv.z, acc[0][2]);
            acc[0][3] = fmaf(av.x, bv.w, acc[0][3]);
            acc[1][0] = fmaf(av.y, bv.x, acc[1][0]);
            acc[1][1] = fmaf(av.y, bv.y, acc[1][1]);
            acc[1][2] = fmaf(av.y, bv.z, acc[1][2]);
            acc[1][3] = fmaf(av.y, bv.w, acc[1][3]);
            acc[2][0] = fmaf(av.z, bv.x, acc[2][0]);
            acc[2][1] = fmaf(av.z, bv.y, acc[2][1]);
            acc[2][2] = fmaf(av.z, bv.z, acc[2][2]);
            acc[2][3] = fmaf(av.z, bv.w, acc[2][3]);
            acc[3][0] = fmaf(av.w, bv.x, acc[3][0]);
            acc[3][1] = fmaf(av.w, bv.y, acc[3][1]);
            acc[3][2] = fmaf(av.w, bv.z, acc[3][2]);
            acc[3][3] = fmaf(av.w, bv.w, acc[3][3]);
        }
        __syncthreads();
    }

    #pragma unroll
    for (int i = 0; i < 4; ++i) {
        int r = m0 + mt + i;
        #pragma unroll
        for (int j = 0; j < 4; ++j) {
            int c = n0 + nt + j;
            if (c < N) {
                float val = acc[i][j] + bias[c];
                if (res) val += res[(size_t)r * N + c];
                C[(size_t)r * N + c] = val;
            }
        }
    }
}

// ---------------------------------------------------------------------------
// Row softmax over 1000 logits -> d_out
// ---------------------------------------------------------------------------
__global__ __launch_bounds__(256) void k_softmax(
    const float* __restrict__ logits, float* __restrict__ out)
{
    int b = blockIdx.x, tid = threadIdx.x;
    __shared__ float red[8];
    float v[4];
    #pragma unroll
    for (int i = 0; i < 4; ++i) {
        int idx = tid + (i << 8);
        v[i] = (idx < 1000) ? logits[(size_t)b * 1000 + idx] : -INFINITY;
    }
    float mx = fmaxf(fmaxf(v[0], v[1]), fmaxf(v[2], v[3]));
    mx = block_max(mx, red);
    float e[4]; float s = 0.f;
    #pragma unroll
    for (int i = 0; i < 4; ++i) {
        int idx = tid + (i << 8);
        e[i] = (idx < 1000) ? expf(v[i] - mx) : 0.f;
        s += e[i];
    }
    s = block_sum(s, red);
    float inv = 1.f / s;
    #pragma unroll
    for (int i = 0; i < 4; ++i) {
        int idx = tid + (i << 8);
        if (idx < 1000) out[(size_t)b * 1000 + idx] = e[i] * inv;
    }
}

// ---------------------------------------------------------------------------
extern "C" void kernel_launch(void* const* d_in, const int* in_sizes, int n_in,
                              void* d_out, int out_size, void* d_ws, size_t ws_size,
                              hipStream_t stream)
{
    const float* x    = (const float*)d_in[0];
    const float* cls  = (const float*)d_in[1];
    const float* Wp   = (const float*)d_in[2];
    const float* ln1w = (const float*)d_in[3];
    const float* ln1b = (const float*)d_in[4];
    const float* Wq   = (const float*)d_in[5];
    const float* bq   = (const float*)d_in[6];
    const float* Wk   = (const float*)d_in[7];
    const float* bk   = (const float*)d_in[8];
    const float* Wv   = (const float*)d_in[9];
    const float* bv   = (const float*)d_in[10];
    const float* ln2w = (const float*)d_in[11];
    const float* ln2b = (const float*)d_in[12];
    const float* Wm   = (const float*)d_in[13];
    const float* bm   = (const float*)d_in[14];
    const float* Wh   = (const float*)d_in[15];
    const float* bh   = (const float*)d_in[16];
    float* out = (float*)d_out;

    char* ws = (char*)d_ws;
    size_t off = 0;
    auto alloc = [&](size_t nfloats) -> float* {
        float* p = (float*)(ws + off);
        off += ((nfloats * 4 + 255) & ~(size_t)255);
        return p;
    };
    float* pe     = alloc(50 * 1024);
    float* tok0   = alloc(1024 * 1024);
    float* A0     = alloc(1024 * 1024);
    float* n2     = alloc(1024 * 1024);
    float* t2     = alloc(1024 * 1024);
    float* logits = alloc(1024 * 1000);
    size_t fixed = off;

    auto alsz = [](size_t n) { return ((n * 4 + 255) & ~(size_t)255); };
    int chunk = 32;
    const int cands[6] = {1024, 512, 256, 128, 64, 32};
    for (int ci = 0; ci < 6; ++ci) {
        int c = cands[ci];
        size_t need = fixed + alsz((size_t)c * 50 * 1024) + 2 * alsz((size_t)c * 50);
        if (need <= ws_size) { chunk = c; break; }
    }
    float* tokc = alloc((size_t)chunk * 50 * 1024);
    float* mu_c = alloc((size_t)chunk * 50);
    float* rs_c = alloc((size_t)chunk * 50);

    k_pe<<<50, 256, 0, stream>>>(pe);

    for (int b0 = 0; b0 < 1024; b0 += chunk) {
        k_embed<<<chunk * 50, 256, 0, stream>>>(x, cls, Wp, pe, tokc, mu_c, rs_c,
                                                tok0, b0);
        k_attn<<<dim3(16, chunk), 256, 0, stream>>>(tokc, mu_c, rs_c, ln1w, ln1b,
                                                    Wq, bq, Wk, bk, Wv, bv, A0, b0);
    }

    k_c1<<<1024, 256, 0, stream>>>(tok0, A0, ln2w, ln2b, n2);
    k_gemm<<<dim3(16, 16), 256, 0, stream>>>(n2, Wm, bm, tok0, t2, 1024, 1024);
    k_gemm<<<dim3(16, 16), 256, 0, stream>>>(t2, Wh, bh, nullptr, logits, 1000, 1024);
    k_softmax<<<1024, 256, 0, stream>>>(logits, out);
}

// Round 4
// 725.536 us; speedup vs baseline: 2.4092x; 2.4092x over previous
//
#include <hip/hip_runtime.h>
#include <math.h>

// ---------------------------------------------------------------------------
// ViT forward, f32. B=1024, D=1024, H=16, DH=64, S=50, OUT=1000.
// Key algebra: only tok[:,0] feeds the head, so
//   scores = (Wk^T q0) . n_s   (K never materialized; q0.bk is softmax-inv.)
//   A0     = Wv . (sum_s p_s n_s) + bv   (V never materialized)
// Attention FLOPs: 13.4 GF -> 0.6 GF.
// ---------------------------------------------------------------------------

#define EPS 1e-5f

__device__ __forceinline__ float dot4(float4 a, float4 b, float acc) {
    acc = fmaf(a.x, b.x, acc);
    acc = fmaf(a.y, b.y, acc);
    acc = fmaf(a.z, b.z, acc);
    return fmaf(a.w, b.w, acc);
}

__device__ __forceinline__ float warp_sum64(float v) {
    #pragma unroll
    for (int off = 32; off >= 1; off >>= 1) v += __shfl_xor(v, off, 64);
    return v;
}
__device__ __forceinline__ float warp_max64(float v) {
    #pragma unroll
    for (int off = 32; off >= 1; off >>= 1) v = fmaxf(v, __shfl_xor(v, off, 64));
    return v;
}

__device__ __forceinline__ float block_sum(float v, float* red) {
    v = warp_sum64(v);
    int lane = threadIdx.x & 63, w = threadIdx.x >> 6;
    if (lane == 0) red[w] = v;
    __syncthreads();
    int nw = blockDim.x >> 6;
    if (w == 0) {
        float x = (lane < nw) ? red[lane] : 0.f;
        x = warp_sum64(x);
        if (lane == 0) red[0] = x;
    }
    __syncthreads();
    float r = red[0];
    __syncthreads();
    return r;
}

__device__ __forceinline__ float block_max(float v, float* red) {
    v = warp_max64(v);
    int lane = threadIdx.x & 63, w = threadIdx.x >> 6;
    if (lane == 0) red[w] = v;
    __syncthreads();
    int nw = blockDim.x >> 6;
    if (w == 0) {
        float x = (lane < nw) ? red[lane] : -INFINITY;
        x = warp_max64(x);
        if (lane == 0) red[0] = x;
    }
    __syncthreads();
    float r = red[0];
    __syncthreads();
    return r;
}

// ---------------------------------------------------------------------------
// PE table
// ---------------------------------------------------------------------------
__global__ __launch_bounds__(256) void k_pe(float* __restrict__ pe) {
    int s = blockIdx.x;
    for (int d = threadIdx.x; d < 1024; d += 256) {
        int di = d & ~1;
        float freq = expf(-((float)di * (1.0f / 1024.f)) * 9.210340371976184f);
        float arg = (float)s * freq;
        pe[s * 1024 + d] = (d & 1) ? cosf(arg) : sinf(arg);
    }
}

// ---------------------------------------------------------------------------
// Embed v2: one block per batch. Wp rows (4 per thread) pinned in 64 VGPRs,
// patch pixels broadcast from LDS. 50 rows sequentially, 2 barriers/row via
// rotating reduction slots. Writes tokc + LN1 stats; row 0 also to tok0.
// ---------------------------------------------------------------------------
__global__ __launch_bounds__(256) void k_embed2(
    const float* __restrict__ x, const float* __restrict__ cls,
    const float* __restrict__ Wp, const float* __restrict__ pe,
    float* __restrict__ tokc, float* __restrict__ mu_c, float* __restrict__ rs_c,
    float* __restrict__ tok0, int b0)
{
    int bc = blockIdx.x, b = b0 + bc, t = threadIdx.x;
    __shared__ __align__(16) float xs[784];
    __shared__ float redbuf[4][4];

    // Wp rows 4t..4t+3 (64 floats) into registers — reused for all 49 patches
    float4 wp[16];
    const float4* wpg = (const float4*)(Wp + ((size_t)t << 6));
    #pragma unroll
    for (int i = 0; i < 16; ++i) wp[i] = wpg[i];

    for (int i = t; i < 784; i += 256) xs[i] = x[(size_t)b * 784 + i];
    __syncthreads();

    for (int s = 0; s < 50; ++s) {
        float tv[4];
        if (s == 0) {
            float4 c4 = *(const float4*)(cls + (t << 2));
            float4 p4 = *(const float4*)(pe + (t << 2));
            tv[0] = c4.x + p4.x; tv[1] = c4.y + p4.y;
            tv[2] = c4.z + p4.z; tv[3] = c4.w + p4.w;
        } else {
            int p = s - 1, pr = p / 7, pc = p % 7;
            const float* px = xs + pr * 112 + pc * 4;
            float4 p0 = make_float4(px[0],  px[1],  px[2],  px[3]);
            float4 p1 = make_float4(px[28], px[29], px[30], px[31]);
            float4 p2 = make_float4(px[56], px[57], px[58], px[59]);
            float4 p3 = make_float4(px[84], px[85], px[86], px[87]);
            float4 pe4 = *(const float4*)(pe + s * 1024 + (t << 2));
            float pear[4] = {pe4.x, pe4.y, pe4.z, pe4.w};
            #pragma unroll
            for (int r = 0; r < 4; ++r) {
                float acc = 0.f;
                acc = dot4(wp[r * 4 + 0], p0, acc);
                acc = dot4(wp[r * 4 + 1], p1, acc);
                acc = dot4(wp[r * 4 + 2], p2, acc);
                acc = dot4(wp[r * 4 + 3], p3, acc);
                tv[r] = acc + pear[r];
            }
        }
        // LN1 stats: two-pass, 2 barriers, rotating slots (safe reuse at s+2)
        float* slotA = redbuf[(s & 1) << 1];
        float* slotB = redbuf[((s & 1) << 1) | 1];
        float sm = warp_sum64(tv[0] + tv[1] + tv[2] + tv[3]);
        if ((t & 63) == 0) slotA[t >> 6] = sm;
        __syncthreads();
        float mu = (slotA[0] + slotA[1] + slotA[2] + slotA[3]) * (1.f / 1024.f);
        float d2 = 0.f;
        #pragma unroll
        for (int r = 0; r < 4; ++r) { float dv = tv[r] - mu; d2 = fmaf(dv, dv, d2); }
        d2 = warp_sum64(d2);
        if ((t & 63) == 0) slotB[t >> 6] = d2;
        __syncthreads();
        float var = (slotB[0] + slotB[1] + slotB[2] + slotB[3]) * (1.f / 1024.f);
        float rstd = rsqrtf(var + EPS);
        int row = bc * 50 + s;
        if (t == 0) { mu_c[row] = mu; rs_c[row] = rstd; }
        float4 o = make_float4(tv[0], tv[1], tv[2], tv[3]);
        *(float4*)(tokc + (size_t)row * 1024 + (t << 2)) = o;
        if (s == 0) *(float4*)(tok0 + (size_t)b * 1024 + (t << 2)) = o;
    }
}

// ---------------------------------------------------------------------------
// Attention v2 (low-rank): block = (head, group of 16 batches).
// Weights staged once (65-pad rows: every phase read is stride-1 or
// broadcast — conflict-free). Per batch: stage n -> q0 -> qk=Wk^T q0 ->
// scores -> softmax -> context -> A0 = Wv c + bv. 4-wave partial+reduce.
// LDS = 63.4 KB -> 2 blocks/CU.
// ---------------------------------------------------------------------------
__global__ __launch_bounds__(256) void k_attn2(
    const float* __restrict__ tokc, const float* __restrict__ mu_c,
    const float* __restrict__ rs_c,
    const float* __restrict__ ln1w, const float* __restrict__ ln1b,
    const float* __restrict__ Wq, const float* __restrict__ bq,
    const float* __restrict__ Wk, const float* __restrict__ bk,
    const float* __restrict__ Wv, const float* __restrict__ bv,
    float* __restrict__ A0, int b0)
{
    __shared__ float Wq_t[64 * 65];   // [d][e]
    __shared__ float Wk_s[64 * 65];   // [e][d]
    __shared__ float Wv_t[64 * 65];   // [d][e]
    __shared__ float n_s[50 * 65];    // [s][e]
    __shared__ float part[4 * 64];
    __shared__ float q0s[64], qk_s[64], c_s[64], p_s[64];

    const int h = blockIdx.x, bg = blockIdx.y;
    const int t = threadIdx.x;
    const int lane = t & 63, wq = t >> 6;

    // stage weights once (scalar; coalesced global, <=2-way LDS write conflict)
    const size_t wb = (size_t)h << 12;
    #pragma unroll
    for (int j = 0; j < 16; ++j) {
        int idx = t + (j << 8);
        int e = idx >> 6, d = idx & 63;
        Wq_t[d * 65 + e] = Wq[wb + idx];
        Wk_s[e * 65 + d] = Wk[wb + idx];
        Wv_t[d * 65 + e] = Wv[wb + idx];
    }
    const float lw = ln1w[(h << 6) + lane];
    const float lb = ln1b[(h << 6) + lane];
    float bqr = 0.f, bvr = 0.f;
    if (t < 64) { bqr = bq[(h << 6) + t]; bvr = bv[(h << 6) + t]; }
    // bk skipped: q0.bk is constant over s -> softmax-invariant.

    for (int it = 0; it < 16; ++it) {
        int bc = (bg << 4) + it;
        __syncthreads();   // n_s free of previous batch's readers (+wt visib. 1st)
        // stage n = LN1(tok slice): 50x64, coalesced, mu/rs broadcast per wave
        #pragma unroll
        for (int j = 0; j < 13; ++j) {
            int idx = t + (j << 8);
            if (idx < 3200) {
                int s = idx >> 6, e = idx & 63;
                int row = bc * 50 + s;
                float raw = tokc[(size_t)row * 1024 + (h << 6) + e];
                n_s[s * 65 + e] = (raw - mu_c[row]) * rs_c[row] * lw + lb;
            }
        }
        __syncthreads();
        {   // q0 partials: lane=e, wq = d-quarter
            float acc = 0.f;
            int dbase = wq << 4;
            #pragma unroll
            for (int i = 0; i < 16; ++i) {
                int d = dbase + i;
                acc = fmaf(Wq_t[d * 65 + lane], n_s[d], acc);   // n_s row 0
            }
            part[(wq << 6) + lane] = acc;
        }
        __syncthreads();
        if (t < 64)
            q0s[t] = part[t] + part[64 + t] + part[128 + t] + part[192 + t] + bqr;
        __syncthreads();
        {   // qk partials: lane=d, wq = e-quarter
            float acc = 0.f;
            int ebase = wq << 4;
            #pragma unroll
            for (int i = 0; i < 16; ++i) {
                int e = ebase + i;
                acc = fmaf(Wk_s[e * 65 + lane], q0s[e], acc);
            }
            part[(wq << 6) + lane] = acc;
        }
        __syncthreads();
        if (t < 64)
            qk_s[t] = part[t] + part[64 + t] + part[128 + t] + part[192 + t];
        __syncthreads();
        {   // score partials: lane=s, wq = d-quarter
            float acc = 0.f;
            int dbase = wq << 4;
            if (lane < 50) {
                #pragma unroll
                for (int i = 0; i < 16; ++i) {
                    int d = dbase + i;
                    acc = fmaf(n_s[lane * 65 + d], qk_s[d], acc);
                }
            }
            part[(wq << 6) + lane] = acc;
        }
        __syncthreads();
        if (t < 64) {   // wave 0: reduce + softmax over 50 (scale = *sqrt(1024))
            float sc = (t < 50)
                ? (part[t] + part[64 + t] + part[128 + t] + part[192 + t]) * 32.0f
                : -INFINITY;
            float mx = warp_max64(sc);
            float ex = (t < 50) ? expf(sc - mx) : 0.f;
            float sm = warp_sum64(ex);
            p_s[t] = ex / sm;
        }
        __syncthreads();
        {   // context partials: lane=d, wq = s-range (13/13/13/11)
            float acc = 0.f;
            int s0 = wq * 13, s1 = (s0 + 13 < 50) ? s0 + 13 : 50;
            for (int s = s0; s < s1; ++s)
                acc = fmaf(p_s[s], n_s[s * 65 + lane], acc);
            part[(wq << 6) + lane] = acc;
        }
        __syncthreads();
        if (t < 64)
            c_s[t] = part[t] + part[64 + t] + part[128 + t] + part[192 + t];
        __syncthreads();
        {   // A0 partials: lane=e, wq = d-quarter
            float acc = 0.f;
            int dbase = wq << 4;
            #pragma unroll
            for (int i = 0; i < 16; ++i) {
                int d = dbase + i;
                acc = fmaf(Wv_t[d * 65 + lane], c_s[d], acc);
            }
            part[(wq << 6) + lane] = acc;
        }
        __syncthreads();
        if (t < 64) {
            float a = part[t] + part[64 + t] + part[128 + t] + part[192 + t] + bvr;
            A0[(size_t)(b0 + bc) * 1024 + (h << 6) + t] = a;
        }
    }
}

// ---------------------------------------------------------------------------
// C1: tok0 += A0; LN2 -> n2. One block per b.
// ---------------------------------------------------------------------------
__global__ __launch_bounds__(256) void k_c1(
    float* __restrict__ tok0, const float* __restrict__ A0,
    const float* __restrict__ w2, const float* __restrict__ b2,
    float* __restrict__ n2)
{
    int b = blockIdx.x, tid = threadIdx.x;
    __shared__ float red[8];
    float t[4];
    #pragma unroll
    for (int i = 0; i < 4; ++i) {
        int d = tid + (i << 8);
        t[i] = tok0[(size_t)b * 1024 + d] + A0[(size_t)b * 1024 + d];
    }
    float sum = t[0] + t[1] + t[2] + t[3];
    sum = block_sum(sum, red);
    float mu = sum * (1.f / 1024.f);
    float d2 = 0.f;
    #pragma unroll
    for (int i = 0; i < 4; ++i) { float dv = t[i] - mu; d2 = fmaf(dv, dv, d2); }
    float var = block_sum(d2, red) * (1.f / 1024.f);
    float rstd = rsqrtf(var + EPS);
    #pragma unroll
    for (int i = 0; i < 4; ++i) {
        int d = tid + (i << 8);
        tok0[(size_t)b * 1024 + d] = t[i];
        n2[(size_t)b * 1024 + d] = (t[i] - mu) * rstd * w2[d] + b2[d];
    }
}

// ---------------------------------------------------------------------------
// Tiled f32 GEMM: C[r,c] = (res? res : 0) + bias[c] + sum_k A[r,k]*Bw[c,k]
// ---------------------------------------------------------------------------
__global__ __launch_bounds__(256) void k_gemm(
    const float* __restrict__ A, const float* __restrict__ Bw,
    const float* __restrict__ bias, const float* __restrict__ res,
    float* __restrict__ C, int N, int K)
{
    __shared__ __align__(16) float As[32 * 68];
    __shared__ __align__(16) float Bs[32 * 68];
    int n0 = blockIdx.x * 64, m0 = blockIdx.y * 64;
    int tid = threadIdx.x;
    int mt = (tid & 15) * 4, nt = (tid >> 4) * 4;
    float acc[4][4] = {{0.f}};

    for (int k0 = 0; k0 < K; k0 += 32) {
        for (int idx = tid; idx < 64 * 32; idx += 256) {
            int kk = idx & 31, m = idx >> 5;
            As[kk * 68 + m] = A[(size_t)(m0 + m) * K + k0 + kk];
            float bvv = (n0 + m < N) ? Bw[(size_t)(n0 + m) * K + k0 + kk] : 0.f;
            Bs[kk * 68 + m] = bvv;
        }
        __syncthreads();
        #pragma unroll 8
        for (int kk = 0; kk < 32; ++kk) {
            float4 av = *(const float4*)&As[kk * 68 + mt];
            float4 bv = *(const float4*)&Bs[kk * 68 + nt];
            acc[0][0] = fmaf(av.x, bv.x, acc[0][0]);
            acc[0][1] = fmaf(av.x, bv.y, acc[0][1]);
            acc[0][2] = fmaf(av.x, bv.z, acc[0][2]);
            acc[0][3] = fmaf(av.x, bv.w, acc[0][3]);
            acc[1][0] = fmaf(av.y, bv.x, acc[1][0]);
            acc[1][1] = fmaf(av.y, bv.y, acc[1][1]);
            acc[1][2] = fmaf(av.y, bv.z, acc[1][2]);
            acc[1][3] = fmaf(av.y, bv.w, acc[1][3]);
            acc[2][0] = fmaf(av.z, bv.x, acc[2][0]);
            acc[2][1] = fmaf(av.z, bv.y, acc[2][1]);
            acc[2][2] = fmaf(av.z, bv.z, acc[2][2]);
            acc[2][3] = fmaf(av.z, bv.w, acc[2][3]);
            acc[3][0] = fmaf(av.w, bv.x, acc[3][0]);
            acc[3][1] = fmaf(av.w, bv.y, acc[3][1]);
            acc[3][2] = fmaf(av.w, bv.z, acc[3][2]);
            acc[3][3] = fmaf(av.w, bv.w, acc[3][3]);
        }
        __syncthreads();
    }

    #pragma unroll
    for (int i = 0; i < 4; ++i) {
        int r = m0 + mt + i;
        #pragma unroll
        for (int j = 0; j < 4; ++j) {
            int c = n0 + nt + j;
            if (c < N) {
                float val = acc[i][j] + bias[c];
                if (res) val += res[(size_t)r * N + c];
                C[(size_t)r * N + c] = val;
            }
        }
    }
}

// ---------------------------------------------------------------------------
// Row softmax over 1000 logits -> d_out
// ---------------------------------------------------------------------------
__global__ __launch_bounds__(256) void k_softmax(
    const float* __restrict__ logits, float* __restrict__ out)
{
    int b = blockIdx.x, tid = threadIdx.x;
    __shared__ float red[8];
    float v[4];
    #pragma unroll
    for (int i = 0; i < 4; ++i) {
        int idx = tid + (i << 8);
        v[i] = (idx < 1000) ? logits[(size_t)b * 1000 + idx] : -INFINITY;
    }
    float mx = fmaxf(fmaxf(v[0], v[1]), fmaxf(v[2], v[3]));
    mx = block_max(mx, red);
    float e[4]; float s = 0.f;
    #pragma unroll
    for (int i = 0; i < 4; ++i) {
        int idx = tid + (i << 8);
        e[i] = (idx < 1000) ? expf(v[i] - mx) : 0.f;
        s += e[i];
    }
    s = block_sum(s, red);
    float inv = 1.f / s;
    #pragma unroll
    for (int i = 0; i < 4; ++i) {
        int idx = tid + (i << 8);
        if (idx < 1000) out[(size_t)b * 1000 + idx] = e[i] * inv;
    }
}

// ---------------------------------------------------------------------------
extern "C" void kernel_launch(void* const* d_in, const int* in_sizes, int n_in,
                              void* d_out, int out_size, void* d_ws, size_t ws_size,
                              hipStream_t stream)
{
    const float* x    = (const float*)d_in[0];
    const float* cls  = (const float*)d_in[1];
    const float* Wp   = (const float*)d_in[2];
    const float* ln1w = (const float*)d_in[3];
    const float* ln1b = (const float*)d_in[4];
    const float* Wq   = (const float*)d_in[5];
    const float* bq   = (const float*)d_in[6];
    const float* Wk   = (const float*)d_in[7];
    const float* bk   = (const float*)d_in[8];
    const float* Wv   = (const float*)d_in[9];
    const float* bv   = (const float*)d_in[10];
    const float* ln2w = (const float*)d_in[11];
    const float* ln2b = (const float*)d_in[12];
    const float* Wm   = (const float*)d_in[13];
    const float* bm   = (const float*)d_in[14];
    const float* Wh   = (const float*)d_in[15];
    const float* bh   = (const float*)d_in[16];
    float* out = (float*)d_out;
    (void)bk;   // softmax-invariant (see k_attn2)

    char* ws = (char*)d_ws;
    size_t off = 0;
    auto alloc = [&](size_t nfloats) -> float* {
        float* p = (float*)(ws + off);
        off += ((nfloats * 4 + 255) & ~(size_t)255);
        return p;
    };
    float* pe     = alloc(50 * 1024);
    float* tok0   = alloc(1024 * 1024);
    float* A0     = alloc(1024 * 1024);
    float* n2     = alloc(1024 * 1024);
    float* t2     = alloc(1024 * 1024);
    float* logits = alloc(1024 * 1000);
    size_t fixed = off;

    auto alsz = [](size_t n) { return ((n * 4 + 255) & ~(size_t)255); };
    int chunk = 32;
    const int cands[6] = {1024, 512, 256, 128, 64, 32};
    for (int ci = 0; ci < 6; ++ci) {
        int c = cands[ci];
        size_t need = fixed + alsz((size_t)c * 50 * 1024) + 2 * alsz((size_t)c * 50);
        if (need <= ws_size) { chunk = c; break; }
    }
    float* tokc = alloc((size_t)chunk * 50 * 1024);
    float* mu_c = alloc((size_t)chunk * 50);
    float* rs_c = alloc((size_t)chunk * 50);

    k_pe<<<50, 256, 0, stream>>>(pe);

    for (int b0 = 0; b0 < 1024; b0 += chunk) {
        k_embed2<<<chunk, 256, 0, stream>>>(x, cls, Wp, pe, tokc, mu_c, rs_c,
                                            tok0, b0);
        k_attn2<<<dim3(16, chunk / 16), 256, 0, stream>>>(
            tokc, mu_c, rs_c, ln1w, ln1b, Wq, bq, Wk, bk, Wv, bv, A0, b0);
    }

    k_c1<<<1024, 256, 0, stream>>>(tok0, A0, ln2w, ln2b, n2);
    k_gemm<<<dim3(16, 16), 256, 0, stream>>>(n2, Wm, bm, tok0, t2, 1024, 1024);
    k_gemm<<<dim3(16, 16), 256, 0, stream>>>(t2, Wh, bh, nullptr, logits, 1000, 1024);
    k_softmax<<<1024, 256, 0, stream>>>(logits, out);
}

// Round 8
// 633.258 us; speedup vs baseline: 2.7603x; 1.1457x over previous
//
#include <hip/hip_runtime.h>
#include <math.h>

// ---------------------------------------------------------------------------
// ViT forward, f32. B=1024, D=1024, H=16, DH=64, S=50, OUT=1000.
// Attention collapsed to class-token (low-rank): K,V never materialized.
// GEMMs (MLP row0, head): LDS-free register-panel kernels, split-K=8.
// ---------------------------------------------------------------------------

#define EPS 1e-5f

__device__ __forceinline__ float dot4(float4 a, float4 b, float acc) {
    acc = fmaf(a.x, b.x, acc);
    acc = fmaf(a.y, b.y, acc);
    acc = fmaf(a.z, b.z, acc);
    return fmaf(a.w, b.w, acc);
}

__device__ __forceinline__ float warp_sum64(float v) {
    #pragma unroll
    for (int off = 32; off >= 1; off >>= 1) v += __shfl_xor(v, off, 64);
    return v;
}
__device__ __forceinline__ float warp_max64(float v) {
    #pragma unroll
    for (int off = 32; off >= 1; off >>= 1) v = fmaxf(v, __shfl_xor(v, off, 64));
    return v;
}

__device__ __forceinline__ float block_sum(float v, float* red) {
    v = warp_sum64(v);
    int lane = threadIdx.x & 63, w = threadIdx.x >> 6;
    if (lane == 0) red[w] = v;
    __syncthreads();
    int nw = blockDim.x >> 6;
    if (w == 0) {
        float x = (lane < nw) ? red[lane] : 0.f;
        x = warp_sum64(x);
        if (lane == 0) red[0] = x;
    }
    __syncthreads();
    float r = red[0];
    __syncthreads();
    return r;
}

__device__ __forceinline__ float block_max(float v, float* red) {
    v = warp_max64(v);
    int lane = threadIdx.x & 63, w = threadIdx.x >> 6;
    if (lane == 0) red[w] = v;
    __syncthreads();
    int nw = blockDim.x >> 6;
    if (w == 0) {
        float x = (lane < nw) ? red[lane] : -INFINITY;
        x = warp_max64(x);
        if (lane == 0) red[0] = x;
    }
    __syncthreads();
    float r = red[0];
    __syncthreads();
    return r;
}

// ---------------------------------------------------------------------------
// PE table
// ---------------------------------------------------------------------------
__global__ __launch_bounds__(256) void k_pe(float* __restrict__ pe) {
    int s = blockIdx.x;
    for (int d = threadIdx.x; d < 1024; d += 256) {
        int di = d & ~1;
        float freq = expf(-((float)di * (1.0f / 1024.f)) * 9.210340371976184f);
        float arg = (float)s * freq;
        pe[s * 1024 + d] = (d & 1) ? cosf(arg) : sinf(arg);
    }
}

// ---------------------------------------------------------------------------
// Embed v2: one block per batch. Wp rows (4/thread) pinned in 64 VGPRs.
// ---------------------------------------------------------------------------
__global__ __launch_bounds__(256) void k_embed2(
    const float* __restrict__ x, const float* __restrict__ cls,
    const float* __restrict__ Wp, const float* __restrict__ pe,
    float* __restrict__ tokc, float* __restrict__ mu_c, float* __restrict__ rs_c,
    float* __restrict__ tok0, int b0)
{
    int bc = blockIdx.x, b = b0 + bc, t = threadIdx.x;
    __shared__ __align__(16) float xs[784];
    __shared__ float redbuf[4][4];

    float4 wp[16];
    const float4* wpg = (const float4*)(Wp + ((size_t)t << 6));
    #pragma unroll
    for (int i = 0; i < 16; ++i) wp[i] = wpg[i];

    for (int i = t; i < 784; i += 256) xs[i] = x[(size_t)b * 784 + i];
    __syncthreads();

    for (int s = 0; s < 50; ++s) {
        float tv[4];
        if (s == 0) {
            float4 c4 = *(const float4*)(cls + (t << 2));
            float4 p4 = *(const float4*)(pe + (t << 2));
            tv[0] = c4.x + p4.x; tv[1] = c4.y + p4.y;
            tv[2] = c4.z + p4.z; tv[3] = c4.w + p4.w;
        } else {
            int p = s - 1, pr = p / 7, pc = p % 7;
            const float* px = xs + pr * 112 + pc * 4;
            float4 p0 = make_float4(px[0],  px[1],  px[2],  px[3]);
            float4 p1 = make_float4(px[28], px[29], px[30], px[31]);
            float4 p2 = make_float4(px[56], px[57], px[58], px[59]);
            float4 p3 = make_float4(px[84], px[85], px[86], px[87]);
            float4 pe4 = *(const float4*)(pe + s * 1024 + (t << 2));
            float pear[4] = {pe4.x, pe4.y, pe4.z, pe4.w};
            #pragma unroll
            for (int r = 0; r < 4; ++r) {
                float acc = 0.f;
                acc = dot4(wp[r * 4 + 0], p0, acc);
                acc = dot4(wp[r * 4 + 1], p1, acc);
                acc = dot4(wp[r * 4 + 2], p2, acc);
                acc = dot4(wp[r * 4 + 3], p3, acc);
                tv[r] = acc + pear[r];
            }
        }
        float* slotA = redbuf[(s & 1) << 1];
        float* slotB = redbuf[((s & 1) << 1) | 1];
        float sm = warp_sum64(tv[0] + tv[1] + tv[2] + tv[3]);
        if ((t & 63) == 0) slotA[t >> 6] = sm;
        __syncthreads();
        float mu = (slotA[0] + slotA[1] + slotA[2] + slotA[3]) * (1.f / 1024.f);
        float d2 = 0.f;
        #pragma unroll
        for (int r = 0; r < 4; ++r) { float dv = tv[r] - mu; d2 = fmaf(dv, dv, d2); }
        d2 = warp_sum64(d2);
        if ((t & 63) == 0) slotB[t >> 6] = d2;
        __syncthreads();
        float var = (slotB[0] + slotB[1] + slotB[2] + slotB[3]) * (1.f / 1024.f);
        float rstd = rsqrtf(var + EPS);
        int row = bc * 50 + s;
        if (t == 0) { mu_c[row] = mu; rs_c[row] = rstd; }
        float4 o = make_float4(tv[0], tv[1], tv[2], tv[3]);
        *(float4*)(tokc + (size_t)row * 1024 + (t << 2)) = o;
        if (s == 0) *(float4*)(tok0 + (size_t)b * 1024 + (t << 2)) = o;
    }
}

// ---------------------------------------------------------------------------
// Attention v2 (low-rank): block = (head, group of 16 batches).
// ---------------------------------------------------------------------------
__global__ __launch_bounds__(256) void k_attn2(
    const float* __restrict__ tokc, const float* __restrict__ mu_c,
    const float* __restrict__ rs_c,
    const float* __restrict__ ln1w, const float* __restrict__ ln1b,
    const float* __restrict__ Wq, const float* __restrict__ bq,
    const float* __restrict__ Wk, const float* __restrict__ bk,
    const float* __restrict__ Wv, const float* __restrict__ bv,
    float* __restrict__ A0, int b0)
{
    __shared__ float Wq_t[64 * 65];   // [d][e]
    __shared__ float Wk_s[64 * 65];   // [e][d]
    __shared__ float Wv_t[64 * 65];   // [d][e]
    __shared__ float n_s[50 * 65];    // [s][e]
    __shared__ float part[4 * 64];
    __shared__ float q0s[64], qk_s[64], c_s[64], p_s[64];

    const int h = blockIdx.x, bg = blockIdx.y;
    const int t = threadIdx.x;
    const int lane = t & 63, wq = t >> 6;

    const size_t wb = (size_t)h << 12;
    #pragma unroll
    for (int j = 0; j < 16; ++j) {
        int idx = t + (j << 8);
        int e = idx >> 6, d = idx & 63;
        Wq_t[d * 65 + e] = Wq[wb + idx];
        Wk_s[e * 65 + d] = Wk[wb + idx];
        Wv_t[d * 65 + e] = Wv[wb + idx];
    }
    const float lw = ln1w[(h << 6) + lane];
    const float lb = ln1b[(h << 6) + lane];
    float bqr = 0.f, bvr = 0.f;
    if (t < 64) { bqr = bq[(h << 6) + t]; bvr = bv[(h << 6) + t]; }
    // bk skipped: q0.bk constant over s -> softmax-invariant.

    for (int it = 0; it < 16; ++it) {
        int bc = (bg << 4) + it;
        __syncthreads();
        #pragma unroll
        for (int j = 0; j < 13; ++j) {
            int idx = t + (j << 8);
            if (idx < 3200) {
                int s = idx >> 6, e = idx & 63;
                int row = bc * 50 + s;
                float raw = tokc[(size_t)row * 1024 + (h << 6) + e];
                n_s[s * 65 + e] = (raw - mu_c[row]) * rs_c[row] * lw + lb;
            }
        }
        __syncthreads();
        {
            float acc = 0.f;
            int dbase = wq << 4;
            #pragma unroll
            for (int i = 0; i < 16; ++i) {
                int d = dbase + i;
                acc = fmaf(Wq_t[d * 65 + lane], n_s[d], acc);
            }
            part[(wq << 6) + lane] = acc;
        }
        __syncthreads();
        if (t < 64)
            q0s[t] = part[t] + part[64 + t] + part[128 + t] + part[192 + t] + bqr;
        __syncthreads();
        {
            float acc = 0.f;
            int ebase = wq << 4;
            #pragma unroll
            for (int i = 0; i < 16; ++i) {
                int e = ebase + i;
                acc = fmaf(Wk_s[e * 65 + lane], q0s[e], acc);
            }
            part[(wq << 6) + lane] = acc;
        }
        __syncthreads();
        if (t < 64)
            qk_s[t] = part[t] + part[64 + t] + part[128 + t] + part[192 + t];
        __syncthreads();
        {
            float acc = 0.f;
            int dbase = wq << 4;
            if (lane < 50) {
                #pragma unroll
                for (int i = 0; i < 16; ++i) {
                    int d = dbase + i;
                    acc = fmaf(n_s[lane * 65 + d], qk_s[d], acc);
                }
            }
            part[(wq << 6) + lane] = acc;
        }
        __syncthreads();
        if (t < 64) {
            float sc = (t < 50)
                ? (part[t] + part[64 + t] + part[128 + t] + part[192 + t]) * 32.0f
                : -INFINITY;
            float mx = warp_max64(sc);
            float ex = (t < 50) ? expf(sc - mx) : 0.f;
            float sm = warp_sum64(ex);
            p_s[t] = ex / sm;
        }
        __syncthreads();
        {
            float acc = 0.f;
            int s0 = wq * 13, s1 = (s0 + 13 < 50) ? s0 + 13 : 50;
            for (int s = s0; s < s1; ++s)
                acc = fmaf(p_s[s], n_s[s * 65 + lane], acc);
            part[(wq << 6) + lane] = acc;
        }
        __syncthreads();
        if (t < 64)
            c_s[t] = part[t] + part[64 + t] + part[128 + t] + part[192 + t];
        __syncthreads();
        {
            float acc = 0.f;
            int dbase = wq << 4;
            #pragma unroll
            for (int i = 0; i < 16; ++i) {
                int d = dbase + i;
                acc = fmaf(Wv_t[d * 65 + lane], c_s[d], acc);
            }
            part[(wq << 6) + lane] = acc;
        }
        __syncthreads();
        if (t < 64) {
            float a = part[t] + part[64 + t] + part[128 + t] + part[192 + t] + bvr;
            A0[(size_t)(b0 + bc) * 1024 + (h << 6) + t] = a;
        }
    }
}

// ---------------------------------------------------------------------------
// C1: tok0 += A0; LN2 -> n2. One block per b.
// ---------------------------------------------------------------------------
__global__ __launch_bounds__(256) void k_c1(
    float* __restrict__ tok0, const float* __restrict__ A0,
    const float* __restrict__ w2, const float* __restrict__ b2,
    float* __restrict__ n2)
{
    int b = blockIdx.x, tid = threadIdx.x;
    __shared__ float red[8];
    float t[4];
    #pragma unroll
    for (int i = 0; i < 4; ++i) {
        int d = tid + (i << 8);
        t[i] = tok0[(size_t)b * 1024 + d] + A0[(size_t)b * 1024 + d];
    }
    float sum = t[0] + t[1] + t[2] + t[3];
    sum = block_sum(sum, red);
    float mu = sum * (1.f / 1024.f);
    float d2 = 0.f;
    #pragma unroll
    for (int i = 0; i < 4; ++i) { float dv = t[i] - mu; d2 = fmaf(dv, dv, d2); }
    float var = block_sum(d2, red) * (1.f / 1024.f);
    float rstd = rsqrtf(var + EPS);
    #pragma unroll
    for (int i = 0; i < 4; ++i) {
        int d = tid + (i << 8);
        tok0[(size_t)b * 1024 + d] = t[i];
        n2[(size_t)b * 1024 + d] = (t[i] - mu) * rstd * w2[d] + b2[d];
    }
}

// ---------------------------------------------------------------------------
// Register-panel GEMM, no LDS. Cp[kz][r][c] = sum_{k in kz-slice} A[r,k]*B[c,k]
// Block = 1 wave (64 thr), lane = output col c. B-tile B[c][k0..k0+127] pinned
// in 128 VGPRs (32 float4). A values wave-uniform (scalarizes to s_load).
// Grid (N/64, M/64, 8). 2048 blocks -> 8 waves/CU. 8 indep acc chains.
// ---------------------------------------------------------------------------
__global__ __launch_bounds__(64, 2) void k_panel(
    const float* __restrict__ A, const float* __restrict__ Bw,
    float* __restrict__ Cp, int N, int K)
{
    const int lane = threadIdx.x;
    const int n0 = blockIdx.x << 6, m0 = blockIdx.y << 6;
    const int kz = blockIdx.z, k0 = kz << 7;
    const int c = n0 + lane;
    const bool cv = (c < N);

    float4 b4[32];
    {
        const float4* brow = (const float4*)(Bw + (size_t)c * K + k0);
        const float4 z = make_float4(0.f, 0.f, 0.f, 0.f);
        #pragma unroll
        for (int i = 0; i < 32; ++i) b4[i] = cv ? brow[i] : z;
    }

    float* cpb = Cp + (size_t)kz * ((size_t)1024 * N);

    for (int ro = 0; ro < 8; ++ro) {
        const int r = m0 + (ro << 3);
        float acc[8] = {0.f, 0.f, 0.f, 0.f, 0.f, 0.f, 0.f, 0.f};
        #pragma unroll
        for (int kc = 0; kc < 16; ++kc) {
            #pragma unroll
            for (int i = 0; i < 8; ++i) {
                const float4* ar = (const float4*)(A + (size_t)(r + i) * K + k0);
                float4 a0 = ar[kc * 2];
                float4 a1 = ar[kc * 2 + 1];
                acc[i] = dot4(a1, b4[kc * 2 + 1], dot4(a0, b4[kc * 2], acc[i]));
            }
        }
        if (cv) {
            #pragma unroll
            for (int i = 0; i < 8; ++i)
                cpb[(size_t)(r + i) * N + c] = acc[i];
        }
    }
}

// ---------------------------------------------------------------------------
// Reduce split-K partials: C = sum_{kz<8} Cp[kz] + bias + (res?). float4 wide.
// ---------------------------------------------------------------------------
__global__ __launch_bounds__(256) void k_reduce(
    const float* __restrict__ Cp, const float* __restrict__ bias,
    const float* __restrict__ res, float* __restrict__ C, int N)
{
    const int N4 = N >> 2;
    int e4 = blockIdx.x * 256 + threadIdx.x;
    if (e4 >= 1024 * N4) return;
    int r = e4 / N4;
    int c = (e4 - r * N4) << 2;
    size_t off = (size_t)r * N + c;
    const size_t slice = (size_t)1024 * N;
    float4 s = make_float4(0.f, 0.f, 0.f, 0.f);
    #pragma unroll
    for (int kz = 0; kz < 8; ++kz) {
        float4 v = *(const float4*)(Cp + kz * slice + off);
        s.x += v.x; s.y += v.y; s.z += v.z; s.w += v.w;
    }
    float4 bb = *(const float4*)(bias + c);
    s.x += bb.x; s.y += bb.y; s.z += bb.z; s.w += bb.w;
    if (res) {
        float4 rv = *(const float4*)(res + off);
        s.x += rv.x; s.y += rv.y; s.z += rv.z; s.w += rv.w;
    }
    *(float4*)(C + off) = s;
}

// ---------------------------------------------------------------------------
// Row softmax over 1000 logits -> d_out
// ---------------------------------------------------------------------------
__global__ __launch_bounds__(256) void k_softmax(
    const float* __restrict__ logits, float* __restrict__ out)
{
    int b = blockIdx.x, tid = threadIdx.x;
    __shared__ float red[8];
    float v[4];
    #pragma unroll
    for (int i = 0; i < 4; ++i) {
        int idx = tid + (i << 8);
        v[i] = (idx < 1000) ? logits[(size_t)b * 1000 + idx] : -INFINITY;
    }
    float mx = fmaxf(fmaxf(v[0], v[1]), fmaxf(v[2], v[3]));
    mx = block_max(mx, red);
    float e[4]; float s = 0.f;
    #pragma unroll
    for (int i = 0; i < 4; ++i) {
        int idx = tid + (i << 8);
        e[i] = (idx < 1000) ? expf(v[i] - mx) : 0.f;
        s += e[i];
    }
    s = block_sum(s, red);
    float inv = 1.f / s;
    #pragma unroll
    for (int i = 0; i < 4; ++i) {
        int idx = tid + (i << 8);
        if (idx < 1000) out[(size_t)b * 1000 + idx] = e[i] * inv;
    }
}

// ---------------------------------------------------------------------------
extern "C" void kernel_launch(void* const* d_in, const int* in_sizes, int n_in,
                              void* d_out, int out_size, void* d_ws, size_t ws_size,
                              hipStream_t stream)
{
    const float* x    = (const float*)d_in[0];
    const float* cls  = (const float*)d_in[1];
    const float* Wp   = (const float*)d_in[2];
    const float* ln1w = (const float*)d_in[3];
    const float* ln1b = (const float*)d_in[4];
    const float* Wq   = (const float*)d_in[5];
    const float* bq   = (const float*)d_in[6];
    const float* Wk   = (const float*)d_in[7];
    const float* bk   = (const float*)d_in[8];
    const float* Wv   = (const float*)d_in[9];
    const float* bv   = (const float*)d_in[10];
    const float* ln2w = (const float*)d_in[11];
    const float* ln2b = (const float*)d_in[12];
    const float* Wm   = (const float*)d_in[13];
    const float* bm   = (const float*)d_in[14];
    const float* Wh   = (const float*)d_in[15];
    const float* bh   = (const float*)d_in[16];
    float* out = (float*)d_out;
    (void)bk;

    char* ws = (char*)d_ws;
    size_t off = 0;
    auto alloc = [&](size_t nfloats) -> float* {
        float* p = (float*)(ws + off);
        off += ((nfloats * 4 + 255) & ~(size_t)255);
        return p;
    };
    float* pe     = alloc(50 * 1024);
    float* tok0   = alloc(1024 * 1024);
    float* A0     = alloc(1024 * 1024);
    float* n2     = alloc(1024 * 1024);
    float* t2     = alloc(1024 * 1024);
    float* logits = alloc(1024 * 1000);
    float* Cp     = alloc((size_t)8 * 1024 * 1024);   // split-K partials
    size_t fixed = off;

    auto alsz = [](size_t n) { return ((n * 4 + 255) & ~(size_t)255); };
    int chunk = 32;
    const int cands[6] = {1024, 512, 256, 128, 64, 32};
    for (int ci = 0; ci < 6; ++ci) {
        int c = cands[ci];
        size_t need = fixed + alsz((size_t)c * 50 * 1024) + 2 * alsz((size_t)c * 50);
        if (need <= ws_size) { chunk = c; break; }
    }
    float* tokc = alloc((size_t)chunk * 50 * 1024);
    float* mu_c = alloc((size_t)chunk * 50);
    float* rs_c = alloc((size_t)chunk * 50);

    k_pe<<<50, 256, 0, stream>>>(pe);

    for (int b0 = 0; b0 < 1024; b0 += chunk) {
        k_embed2<<<chunk, 256, 0, stream>>>(x, cls, Wp, pe, tokc, mu_c, rs_c,
                                            tok0, b0);
        k_attn2<<<dim3(16, chunk / 16), 256, 0, stream>>>(
            tokc, mu_c, rs_c, ln1w, ln1b, Wq, bq, Wk, bk, Wv, bv, A0, b0);
    }

    k_c1<<<1024, 256, 0, stream>>>(tok0, A0, ln2w, ln2b, n2);

    // MLP GEMM (row 0): t2 = tok0 + n2 @ Wm^T + bm
    k_panel<<<dim3(16, 16, 8), 64, 0, stream>>>(n2, Wm, Cp, 1024, 1024);
    k_reduce<<<1024, 256, 0, stream>>>(Cp, bm, tok0, t2, 1024);

    // Head GEMM: logits = t2 @ Wh^T + bh
    k_panel<<<dim3(16, 16, 8), 64, 0, stream>>>(t2, Wh, Cp, 1000, 1024);
    k_reduce<<<1000, 256, 0, stream>>>(Cp, bh, nullptr, logits, 1000);

    k_softmax<<<1024, 256, 0, stream>>>(logits, out);
}

// Round 9
// 420.744 us; speedup vs baseline: 4.1544x; 1.5051x over previous
//
#include <hip/hip_runtime.h>
#include <math.h>

// ---------------------------------------------------------------------------
// ViT forward, f32. B=1024, D=1024, H=16, DH=64, S=50, OUT=1000.
// Attention collapsed to class-token (low-rank): K,V never materialized.
// GEMMs (MLP row0, head): LDS-tiled 64x64, split-K=8 (8 blocks/CU), f32.
// ---------------------------------------------------------------------------

#define EPS 1e-5f

__device__ __forceinline__ float dot4(float4 a, float4 b, float acc) {
    acc = fmaf(a.x, b.x, acc);
    acc = fmaf(a.y, b.y, acc);
    acc = fmaf(a.z, b.z, acc);
    return fmaf(a.w, b.w, acc);
}

__device__ __forceinline__ float warp_sum64(float v) {
    #pragma unroll
    for (int off = 32; off >= 1; off >>= 1) v += __shfl_xor(v, off, 64);
    return v;
}
__device__ __forceinline__ float warp_max64(float v) {
    #pragma unroll
    for (int off = 32; off >= 1; off >>= 1) v = fmaxf(v, __shfl_xor(v, off, 64));
    return v;
}

__device__ __forceinline__ float block_sum(float v, float* red) {
    v = warp_sum64(v);
    int lane = threadIdx.x & 63, w = threadIdx.x >> 6;
    if (lane == 0) red[w] = v;
    __syncthreads();
    int nw = blockDim.x >> 6;
    if (w == 0) {
        float x = (lane < nw) ? red[lane] : 0.f;
        x = warp_sum64(x);
        if (lane == 0) red[0] = x;
    }
    __syncthreads();
    float r = red[0];
    __syncthreads();
    return r;
}

__device__ __forceinline__ float block_max(float v, float* red) {
    v = warp_max64(v);
    int lane = threadIdx.x & 63, w = threadIdx.x >> 6;
    if (lane == 0) red[w] = v;
    __syncthreads();
    int nw = blockDim.x >> 6;
    if (w == 0) {
        float x = (lane < nw) ? red[lane] : -INFINITY;
        x = warp_max64(x);
        if (lane == 0) red[0] = x;
    }
    __syncthreads();
    float r = red[0];
    __syncthreads();
    return r;
}

// ---------------------------------------------------------------------------
// PE table
// ---------------------------------------------------------------------------
__global__ __launch_bounds__(256) void k_pe(float* __restrict__ pe) {
    int s = blockIdx.x;
    for (int d = threadIdx.x; d < 1024; d += 256) {
        int di = d & ~1;
        float freq = expf(-((float)di * (1.0f / 1024.f)) * 9.210340371976184f);
        float arg = (float)s * freq;
        pe[s * 1024 + d] = (d & 1) ? cosf(arg) : sinf(arg);
    }
}

// ---------------------------------------------------------------------------
// Embed v2: one block per batch. Wp rows (4/thread) pinned in 64 VGPRs.
// ---------------------------------------------------------------------------
__global__ __launch_bounds__(256) void k_embed2(
    const float* __restrict__ x, const float* __restrict__ cls,
    const float* __restrict__ Wp, const float* __restrict__ pe,
    float* __restrict__ tokc, float* __restrict__ mu_c, float* __restrict__ rs_c,
    float* __restrict__ tok0, int b0)
{
    int bc = blockIdx.x, b = b0 + bc, t = threadIdx.x;
    __shared__ __align__(16) float xs[784];
    __shared__ float redbuf[4][4];

    float4 wp[16];
    const float4* wpg = (const float4*)(Wp + ((size_t)t << 6));
    #pragma unroll
    for (int i = 0; i < 16; ++i) wp[i] = wpg[i];

    for (int i = t; i < 784; i += 256) xs[i] = x[(size_t)b * 784 + i];
    __syncthreads();

    for (int s = 0; s < 50; ++s) {
        float tv[4];
        if (s == 0) {
            float4 c4 = *(const float4*)(cls + (t << 2));
            float4 p4 = *(const float4*)(pe + (t << 2));
            tv[0] = c4.x + p4.x; tv[1] = c4.y + p4.y;
            tv[2] = c4.z + p4.z; tv[3] = c4.w + p4.w;
        } else {
            int p = s - 1, pr = p / 7, pc = p % 7;
            const float* px = xs + pr * 112 + pc * 4;
            float4 p0 = make_float4(px[0],  px[1],  px[2],  px[3]);
            float4 p1 = make_float4(px[28], px[29], px[30], px[31]);
            float4 p2 = make_float4(px[56], px[57], px[58], px[59]);
            float4 p3 = make_float4(px[84], px[85], px[86], px[87]);
            float4 pe4 = *(const float4*)(pe + s * 1024 + (t << 2));
            float pear[4] = {pe4.x, pe4.y, pe4.z, pe4.w};
            #pragma unroll
            for (int r = 0; r < 4; ++r) {
                float acc = 0.f;
                acc = dot4(wp[r * 4 + 0], p0, acc);
                acc = dot4(wp[r * 4 + 1], p1, acc);
                acc = dot4(wp[r * 4 + 2], p2, acc);
                acc = dot4(wp[r * 4 + 3], p3, acc);
                tv[r] = acc + pear[r];
            }
        }
        float* slotA = redbuf[(s & 1) << 1];
        float* slotB = redbuf[((s & 1) << 1) | 1];
        float sm = warp_sum64(tv[0] + tv[1] + tv[2] + tv[3]);
        if ((t & 63) == 0) slotA[t >> 6] = sm;
        __syncthreads();
        float mu = (slotA[0] + slotA[1] + slotA[2] + slotA[3]) * (1.f / 1024.f);
        float d2 = 0.f;
        #pragma unroll
        for (int r = 0; r < 4; ++r) { float dv = tv[r] - mu; d2 = fmaf(dv, dv, d2); }
        d2 = warp_sum64(d2);
        if ((t & 63) == 0) slotB[t >> 6] = d2;
        __syncthreads();
        float var = (slotB[0] + slotB[1] + slotB[2] + slotB[3]) * (1.f / 1024.f);
        float rstd = rsqrtf(var + EPS);
        int row = bc * 50 + s;
        if (t == 0) { mu_c[row] = mu; rs_c[row] = rstd; }
        float4 o = make_float4(tv[0], tv[1], tv[2], tv[3]);
        *(float4*)(tokc + (size_t)row * 1024 + (t << 2)) = o;
        if (s == 0) *(float4*)(tok0 + (size_t)b * 1024 + (t << 2)) = o;
    }
}

// ---------------------------------------------------------------------------
// Attention v2 (low-rank): block = (head, group of 16 batches).
// ---------------------------------------------------------------------------
__global__ __launch_bounds__(256) void k_attn2(
    const float* __restrict__ tokc, const float* __restrict__ mu_c,
    const float* __restrict__ rs_c,
    const float* __restrict__ ln1w, const float* __restrict__ ln1b,
    const float* __restrict__ Wq, const float* __restrict__ bq,
    const float* __restrict__ Wk, const float* __restrict__ bk,
    const float* __restrict__ Wv, const float* __restrict__ bv,
    float* __restrict__ A0, int b0)
{
    __shared__ float Wq_t[64 * 65];   // [d][e]
    __shared__ float Wk_s[64 * 65];   // [e][d]
    __shared__ float Wv_t[64 * 65];   // [d][e]
    __shared__ float n_s[50 * 65];    // [s][e]
    __shared__ float part[4 * 64];
    __shared__ float q0s[64], qk_s[64], c_s[64], p_s[64];

    const int h = blockIdx.x, bg = blockIdx.y;
    const int t = threadIdx.x;
    const int lane = t & 63, wq = t >> 6;

    const size_t wb = (size_t)h << 12;
    #pragma unroll
    for (int j = 0; j < 16; ++j) {
        int idx = t + (j << 8);
        int e = idx >> 6, d = idx & 63;
        Wq_t[d * 65 + e] = Wq[wb + idx];
        Wk_s[e * 65 + d] = Wk[wb + idx];
        Wv_t[d * 65 + e] = Wv[wb + idx];
    }
    const float lw = ln1w[(h << 6) + lane];
    const float lb = ln1b[(h << 6) + lane];
    float bqr = 0.f, bvr = 0.f;
    if (t < 64) { bqr = bq[(h << 6) + t]; bvr = bv[(h << 6) + t]; }
    // bk skipped: q0.bk constant over s -> softmax-invariant.

    for (int it = 0; it < 16; ++it) {
        int bc = (bg << 4) + it;
        __syncthreads();
        #pragma unroll
        for (int j = 0; j < 13; ++j) {
            int idx = t + (j << 8);
            if (idx < 3200) {
                int s = idx >> 6, e = idx & 63;
                int row = bc * 50 + s;
                float raw = tokc[(size_t)row * 1024 + (h << 6) + e];
                n_s[s * 65 + e] = (raw - mu_c[row]) * rs_c[row] * lw + lb;
            }
        }
        __syncthreads();
        {
            float acc = 0.f;
            int dbase = wq << 4;
            #pragma unroll
            for (int i = 0; i < 16; ++i) {
                int d = dbase + i;
                acc = fmaf(Wq_t[d * 65 + lane], n_s[d], acc);
            }
            part[(wq << 6) + lane] = acc;
        }
        __syncthreads();
        if (t < 64)
            q0s[t] = part[t] + part[64 + t] + part[128 + t] + part[192 + t] + bqr;
        __syncthreads();
        {
            float acc = 0.f;
            int ebase = wq << 4;
            #pragma unroll
            for (int i = 0; i < 16; ++i) {
                int e = ebase + i;
                acc = fmaf(Wk_s[e * 65 + lane], q0s[e], acc);
            }
            part[(wq << 6) + lane] = acc;
        }
        __syncthreads();
        if (t < 64)
            qk_s[t] = part[t] + part[64 + t] + part[128 + t] + part[192 + t];
        __syncthreads();
        {
            float acc = 0.f;
            int dbase = wq << 4;
            if (lane < 50) {
                #pragma unroll
                for (int i = 0; i < 16; ++i) {
                    int d = dbase + i;
                    acc = fmaf(n_s[lane * 65 + d], qk_s[d], acc);
                }
            }
            part[(wq << 6) + lane] = acc;
        }
        __syncthreads();
        if (t < 64) {
            float sc = (t < 50)
                ? (part[t] + part[64 + t] + part[128 + t] + part[192 + t]) * 32.0f
                : -INFINITY;
            float mx = warp_max64(sc);
            float ex = (t < 50) ? expf(sc - mx) : 0.f;
            float sm = warp_sum64(ex);
            p_s[t] = ex / sm;
        }
        __syncthreads();
        {
            float acc = 0.f;
            int s0 = wq * 13, s1 = (s0 + 13 < 50) ? s0 + 13 : 50;
            for (int s = s0; s < s1; ++s)
                acc = fmaf(p_s[s], n_s[s * 65 + lane], acc);
            part[(wq << 6) + lane] = acc;
        }
        __syncthreads();
        if (t < 64)
            c_s[t] = part[t] + part[64 + t] + part[128 + t] + part[192 + t];
        __syncthreads();
        {
            float acc = 0.f;
            int dbase = wq << 4;
            #pragma unroll
            for (int i = 0; i < 16; ++i) {
                int d = dbase + i;
                acc = fmaf(Wv_t[d * 65 + lane], c_s[d], acc);
            }
            part[(wq << 6) + lane] = acc;
        }
        __syncthreads();
        if (t < 64) {
            float a = part[t] + part[64 + t] + part[128 + t] + part[192 + t] + bvr;
            A0[(size_t)(b0 + bc) * 1024 + (h << 6) + t] = a;
        }
    }
}

// ---------------------------------------------------------------------------
// C1: tok0 += A0; LN2 -> n2. One block per b.
// ---------------------------------------------------------------------------
__global__ __launch_bounds__(256) void k_c1(
    float* __restrict__ tok0, const float* __restrict__ A0,
    const float* __restrict__ w2, const float* __restrict__ b2,
    float* __restrict__ n2)
{
    int b = blockIdx.x, tid = threadIdx.x;
    __shared__ float red[8];
    float t[4];
    #pragma unroll
    for (int i = 0; i < 4; ++i) {
        int d = tid + (i << 8);
        t[i] = tok0[(size_t)b * 1024 + d] + A0[(size_t)b * 1024 + d];
    }
    float sum = t[0] + t[1] + t[2] + t[3];
    sum = block_sum(sum, red);
    float mu = sum * (1.f / 1024.f);
    float d2 = 0.f;
    #pragma unroll
    for (int i = 0; i < 4; ++i) { float dv = t[i] - mu; d2 = fmaf(dv, dv, d2); }
    float var = block_sum(d2, red) * (1.f / 1024.f);
    float rstd = rsqrtf(var + EPS);
    #pragma unroll
    for (int i = 0; i < 4; ++i) {
        int d = tid + (i << 8);
        tok0[(size_t)b * 1024 + d] = t[i];
        n2[(size_t)b * 1024 + d] = (t[i] - mu) * rstd * w2[d] + b2[d];
    }
}

// ---------------------------------------------------------------------------
// Split-K LDS-tiled f32 GEMM. Cp[kz][r][c] = sum_{k in kz*128..+128} A[r,k]*B[c,k]
// 64x64 tile, BK=32, 256 threads, 4x4 microtile. Grid (N/64, 16, 8) = 2048
// blocks = 8 blocks/CU = 32 waves/CU (occupancy fix vs round-4's 1 block/CU).
// ---------------------------------------------------------------------------
__global__ __launch_bounds__(256) void k_gemm_sk(
    const float* __restrict__ A, const float* __restrict__ Bw,
    float* __restrict__ Cp, int N, int K)
{
    __shared__ __align__(16) float As[32 * 68];
    __shared__ __align__(16) float Bs[32 * 68];
    int n0 = blockIdx.x * 64, m0 = blockIdx.y * 64;
    int kz = blockIdx.z;
    int tid = threadIdx.x;
    int mt = (tid & 15) * 4, nt = (tid >> 4) * 4;
    float acc[4][4] = {{0.f}};

    int kbeg = kz * 128;
    for (int k0 = kbeg; k0 < kbeg + 128; k0 += 32) {
        for (int idx = tid; idx < 64 * 32; idx += 256) {
            int kk = idx & 31, m = idx >> 5;
            As[kk * 68 + m] = A[(size_t)(m0 + m) * K + k0 + kk];
            float bvv = (n0 + m < N) ? Bw[(size_t)(n0 + m) * K + k0 + kk] : 0.f;
            Bs[kk * 68 + m] = bvv;
        }
        __syncthreads();
        #pragma unroll 8
        for (int kk = 0; kk < 32; ++kk) {
            float4 av = *(const float4*)&As[kk * 68 + mt];
            float4 bv = *(const float4*)&Bs[kk * 68 + nt];
            acc[0][0] = fmaf(av.x, bv.x, acc[0][0]);
            acc[0][1] = fmaf(av.x, bv.y, acc[0][1]);
            acc[0][2] = fmaf(av.x, bv.z, acc[0][2]);
            acc[0][3] = fmaf(av.x, bv.w, acc[0][3]);
            acc[1][0] = fmaf(av.y, bv.x, acc[1][0]);
            acc[1][1] = fmaf(av.y, bv.y, acc[1][1]);
            acc[1][2] = fmaf(av.y, bv.z, acc[1][2]);
            acc[1][3] = fmaf(av.y, bv.w, acc[1][3]);
            acc[2][0] = fmaf(av.z, bv.x, acc[2][0]);
            acc[2][1] = fmaf(av.z, bv.y, acc[2][1]);
            acc[2][2] = fmaf(av.z, bv.z, acc[2][2]);
            acc[2][3] = fmaf(av.z, bv.w, acc[2][3]);
            acc[3][0] = fmaf(av.w, bv.x, acc[3][0]);
            acc[3][1] = fmaf(av.w, bv.y, acc[3][1]);
            acc[3][2] = fmaf(av.w, bv.z, acc[3][2]);
            acc[3][3] = fmaf(av.w, bv.w, acc[3][3]);
        }
        __syncthreads();
    }

    float* cpb = Cp + (size_t)kz * ((size_t)1024 * N);
    #pragma unroll
    for (int i = 0; i < 4; ++i) {
        int r = m0 + mt + i;
        #pragma unroll
        for (int j = 0; j < 4; ++j) {
            int c = n0 + nt + j;
            if (c < N) cpb[(size_t)r * N + c] = acc[i][j];
        }
    }
}

// ---------------------------------------------------------------------------
// Reduce split-K partials: C = sum_{kz<8} Cp[kz] + bias + (res?). float4 wide.
// ---------------------------------------------------------------------------
__global__ __launch_bounds__(256) void k_reduce(
    const float* __restrict__ Cp, const float* __restrict__ bias,
    const float* __restrict__ res, float* __restrict__ C, int N)
{
    const int N4 = N >> 2;
    int e4 = blockIdx.x * 256 + threadIdx.x;
    if (e4 >= 1024 * N4) return;
    int r = e4 / N4;
    int c = (e4 - r * N4) << 2;
    size_t off = (size_t)r * N + c;
    const size_t slice = (size_t)1024 * N;
    float4 s = make_float4(0.f, 0.f, 0.f, 0.f);
    #pragma unroll
    for (int kz = 0; kz < 8; ++kz) {
        float4 v = *(const float4*)(Cp + kz * slice + off);
        s.x += v.x; s.y += v.y; s.z += v.z; s.w += v.w;
    }
    float4 bb = *(const float4*)(bias + c);
    s.x += bb.x; s.y += bb.y; s.z += bb.z; s.w += bb.w;
    if (res) {
        float4 rv = *(const float4*)(res + off);
        s.x += rv.x; s.y += rv.y; s.z += rv.z; s.w += rv.w;
    }
    *(float4*)(C + off) = s;
}

// ---------------------------------------------------------------------------
// Row softmax over 1000 logits -> d_out
// ---------------------------------------------------------------------------
__global__ __launch_bounds__(256) void k_softmax(
    const float* __restrict__ logits, float* __restrict__ out)
{
    int b = blockIdx.x, tid = threadIdx.x;
    __shared__ float red[8];
    float v[4];
    #pragma unroll
    for (int i = 0; i < 4; ++i) {
        int idx = tid + (i << 8);
        v[i] = (idx < 1000) ? logits[(size_t)b * 1000 + idx] : -INFINITY;
    }
    float mx = fmaxf(fmaxf(v[0], v[1]), fmaxf(v[2], v[3]));
    mx = block_max(mx, red);
    float e[4]; float s = 0.f;
    #pragma unroll
    for (int i = 0; i < 4; ++i) {
        int idx = tid + (i << 8);
        e[i] = (idx < 1000) ? expf(v[i] - mx) : 0.f;
        s += e[i];
    }
    s = block_sum(s, red);
    float inv = 1.f / s;
    #pragma unroll
    for (int i = 0; i < 4; ++i) {
        int idx = tid + (i << 8);
        if (idx < 1000) out[(size_t)b * 1000 + idx] = e[i] * inv;
    }
}

// ---------------------------------------------------------------------------
extern "C" void kernel_launch(void* const* d_in, const int* in_sizes, int n_in,
                              void* d_out, int out_size, void* d_ws, size_t ws_size,
                              hipStream_t stream)
{
    const float* x    = (const float*)d_in[0];
    const float* cls  = (const float*)d_in[1];
    const float* Wp   = (const float*)d_in[2];
    const float* ln1w = (const float*)d_in[3];
    const float* ln1b = (const float*)d_in[4];
    const float* Wq   = (const float*)d_in[5];
    const float* bq   = (const float*)d_in[6];
    const float* Wk   = (const float*)d_in[7];
    const float* bk   = (const float*)d_in[8];
    const float* Wv   = (const float*)d_in[9];
    const float* bv   = (const float*)d_in[10];
    const float* ln2w = (const float*)d_in[11];
    const float* ln2b = (const float*)d_in[12];
    const float* Wm   = (const float*)d_in[13];
    const float* bm   = (const float*)d_in[14];
    const float* Wh   = (const float*)d_in[15];
    const float* bh   = (const float*)d_in[16];
    float* out = (float*)d_out;
    (void)bk;

    char* ws = (char*)d_ws;
    size_t off = 0;
    auto alloc = [&](size_t nfloats) -> float* {
        float* p = (float*)(ws + off);
        off += ((nfloats * 4 + 255) & ~(size_t)255);
        return p;
    };
    float* pe     = alloc(50 * 1024);
    float* tok0   = alloc(1024 * 1024);
    float* A0     = alloc(1024 * 1024);
    float* n2     = alloc(1024 * 1024);
    float* t2     = alloc(1024 * 1024);
    float* logits = alloc(1024 * 1000);
    float* Cp     = alloc((size_t)8 * 1024 * 1024);   // split-K partials
    size_t fixed = off;

    auto alsz = [](size_t n) { return ((n * 4 + 255) & ~(size_t)255); };
    int chunk = 32;
    const int cands[6] = {1024, 512, 256, 128, 64, 32};
    for (int ci = 0; ci < 6; ++ci) {
        int c = cands[ci];
        size_t need = fixed + alsz((size_t)c * 50 * 1024) + 2 * alsz((size_t)c * 50);
        if (need <= ws_size) { chunk = c; break; }
    }
    float* tokc = alloc((size_t)chunk * 50 * 1024);
    float* mu_c = alloc((size_t)chunk * 50);
    float* rs_c = alloc((size_t)chunk * 50);

    k_pe<<<50, 256, 0, stream>>>(pe);

    for (int b0 = 0; b0 < 1024; b0 += chunk) {
        k_embed2<<<chunk, 256, 0, stream>>>(x, cls, Wp, pe, tokc, mu_c, rs_c,
                                            tok0, b0);
        k_attn2<<<dim3(16, chunk / 16), 256, 0, stream>>>(
            tokc, mu_c, rs_c, ln1w, ln1b, Wq, bq, Wk, bk, Wv, bv, A0, b0);
    }

    k_c1<<<1024, 256, 0, stream>>>(tok0, A0, ln2w, ln2b, n2);

    // MLP GEMM (row 0): t2 = tok0 + n2 @ Wm^T + bm
    k_gemm_sk<<<dim3(16, 16, 8), 256, 0, stream>>>(n2, Wm, Cp, 1024, 1024);
    k_reduce<<<1024, 256, 0, stream>>>(Cp, bm, tok0, t2, 1024);

    // Head GEMM: logits = t2 @ Wh^T + bh
    k_gemm_sk<<<dim3(16, 16, 8), 256, 0, stream>>>(t2, Wh, Cp, 1000, 1024);
    k_reduce<<<1000, 256, 0, stream>>>(Cp, bh, nullptr, logits, 1000);

    k_softmax<<<1024, 256, 0, stream>>>(logits, out);
}

// Round 11
// 332.133 us; speedup vs baseline: 5.2628x; 1.2668x over previous
//
#include <hip/hip_runtime.h>
#include <math.h>

// ---------------------------------------------------------------------------
// ViT forward, f32. B=1024, D=1024, H=16, DH=64, S=50, OUT=1000.
// Class-token row is BATCH-INDEPENDENT -> qk=Wk^T q0 is a constant; scores и
// LN-stats collapse to 16-dim patch algebra via precomputed tables.
//   score[h,s] = rs_s*(g_h.p_s + pesum[h,s] - mu_s*kappa_h) + beta_h
//   (qk pre-scaled by sqrt(D)=32 -> all score tables inherit the temperature)
//   c = p0*n0 + lw*(Wp.wpatch_h + wpe - wmu_h) + lb*(1-p0);  A0 = Wv c + bv
// GEMMs (MLP row0, head): LDS-tiled 64x64 split-K=8 (measured good, round 9).
// ---------------------------------------------------------------------------

#define EPS 1e-5f

__device__ __forceinline__ float warp_sum64(float v) {
    #pragma unroll
    for (int off = 32; off >= 1; off >>= 1) v += __shfl_xor(v, off, 64);
    return v;
}
__device__ __forceinline__ float warp_max64(float v) {
    #pragma unroll
    for (int off = 32; off >= 1; off >>= 1) v = fmaxf(v, __shfl_xor(v, off, 64));
    return v;
}

__device__ __forceinline__ float block_sum(float v, float* red) {
    v = warp_sum64(v);
    int lane = threadIdx.x & 63, w = threadIdx.x >> 6;
    if (lane == 0) red[w] = v;
    __syncthreads();
    int nw = blockDim.x >> 6;
    if (w == 0) {
        float x = (lane < nw) ? red[lane] : 0.f;
        x = warp_sum64(x);
        if (lane == 0) red[0] = x;
    }
    __syncthreads();
    float r = red[0];
    __syncthreads();
    return r;
}

__device__ __forceinline__ float block_max(float v, float* red) {
    v = warp_max64(v);
    int lane = threadIdx.x & 63, w = threadIdx.x >> 6;
    if (lane == 0) red[w] = v;
    __syncthreads();
    int nw = blockDim.x >> 6;
    if (w == 0) {
        float x = (lane < nw) ? red[lane] : -INFINITY;
        x = warp_max64(x);
        if (lane == 0) red[0] = x;
    }
    __syncthreads();
    float r = red[0];
    __syncthreads();
    return r;
}

// ---------------------------------------------------------------------------
// PE table
// ---------------------------------------------------------------------------
__global__ __launch_bounds__(256) void k_pe(float* __restrict__ pe) {
    int s = blockIdx.x;
    for (int d = threadIdx.x; d < 1024; d += 256) {
        int di = d & ~1;
        float freq = expf(-((float)di * (1.0f / 1024.f)) * 9.210340371976184f);
        float arg = (float)s * freq;
        pe[s * 1024 + d] = (d & 1) ? cosf(arg) : sinf(arg);
    }
}

// ---------------------------------------------------------------------------
// Prep A (1 block): tok0c=cls+pe0, LN1 -> n0; q0 = Wq n0 + bq;
// qk[d] = 32 * sum_e Wk[h][e][dl] q0[e]   (<- sqrt(D) temperature here);
// qlw = qk*ln1w; score0[h]=qk.n0, kappa[h]=sum qlw, beta[h]=qk.lb per head.
// ---------------------------------------------------------------------------
__global__ __launch_bounds__(256) void k_prep_a(
    const float* __restrict__ cls, const float* __restrict__ pe,
    const float* __restrict__ ln1w, const float* __restrict__ ln1b,
    const float* __restrict__ Wq, const float* __restrict__ bq,
    const float* __restrict__ Wk,
    float* __restrict__ tok0c, float* __restrict__ n0g,
    float* __restrict__ qlw,
    float* __restrict__ score0, float* __restrict__ kap, float* __restrict__ bet)
{
    __shared__ float red[8];
    __shared__ float n0s[1024], q0s[1024];
    __shared__ float partA[256], partK[256], partB[256];
    int t = threadIdx.x;
    int h = t >> 4;                    // d/e range 4t..4t+3 lies in head t/16

    float tv[4];
    #pragma unroll
    for (int i = 0; i < 4; ++i) {
        int d = t * 4 + i;
        tv[i] = cls[d] + pe[d];
        tok0c[d] = tv[i];
    }
    float sum = block_sum(tv[0] + tv[1] + tv[2] + tv[3], red);
    float mu = sum * (1.f / 1024.f);
    float d2 = 0.f;
    #pragma unroll
    for (int i = 0; i < 4; ++i) { float dv = tv[i] - mu; d2 = fmaf(dv, dv, d2); }
    float var = block_sum(d2, red) * (1.f / 1024.f);
    float rstd = rsqrtf(var + EPS);
    #pragma unroll
    for (int i = 0; i < 4; ++i) {
        int d = t * 4 + i;
        float nv = (tv[i] - mu) * rstd * ln1w[d] + ln1b[d];
        n0s[d] = nv; n0g[d] = nv;
    }
    __syncthreads();

    #pragma unroll
    for (int i = 0; i < 4; ++i) {
        int e = t * 4 + i, el = e & 63;
        const float* wr = Wq + ((size_t)h << 12) + el * 64;
        float acc = bq[e];
        for (int dd = 0; dd < 64; ++dd) acc = fmaf(wr[dd], n0s[(h << 6) + dd], acc);
        q0s[e] = acc;
    }
    __syncthreads();

    float pA = 0.f, pK = 0.f, pB = 0.f;
    #pragma unroll
    for (int i = 0; i < 4; ++i) {
        int d = t * 4 + i, dl = d & 63;
        const float* wc = Wk + ((size_t)h << 12) + dl;
        float acc = 0.f;
        for (int ee = 0; ee < 64; ++ee) acc = fmaf(wc[ee * 64], q0s[(h << 6) + ee], acc);
        acc *= 32.0f;                  // sqrt(D)=32 score temperature (ROUND-10 BUG FIX)
        float ql = acc * ln1w[d];
        qlw[d] = ql;
        pA = fmaf(acc, n0s[d], pA);
        pK += ql;
        pB = fmaf(acc, ln1b[d], pB);
    }
    partA[t] = pA; partK[t] = pK; partB[t] = pB;
    __syncthreads();
    if (t < 16) {
        float sA = 0.f, sK = 0.f, sB = 0.f;
        #pragma unroll
        for (int i = 0; i < 16; ++i) {
            sA += partA[t * 16 + i]; sK += partK[t * 16 + i]; sB += partB[t * 16 + i];
        }
        score0[t] = sA; kap[t] = sK; bet[t] = sB;
    }
}

// ---------------------------------------------------------------------------
// Prep B (52 blocks): blocks 0..49 -> per-s tables pw[s][16], pe2[s],
// pemean[s], pesum[s][16]; block 50 -> G[16][16], u[16]; block 51 -> g[h][16].
// ---------------------------------------------------------------------------
__global__ __launch_bounds__(256) void k_prep_b(
    const float* __restrict__ pe, const float* __restrict__ Wp,
    const float* __restrict__ qlw,
    float* __restrict__ pwt, float* __restrict__ pe2t,
    float* __restrict__ pemean, float* __restrict__ pesum,
    float* __restrict__ Gt, float* __restrict__ ut, float* __restrict__ gt)
{
    int blk = blockIdx.x, t = threadIdx.x;
    if (blk < 50) {
        __shared__ float red[8];
        __shared__ float pwbuf[256 * 16];
        __shared__ float psbuf[256];
        int s = blk;
        float pwp[16];
        #pragma unroll
        for (int j = 0; j < 16; ++j) pwp[j] = 0.f;
        float pep = 0.f, pe2p = 0.f, psp = 0.f;
        #pragma unroll
        for (int i = 0; i < 4; ++i) {
            int d = t * 4 + i;
            float e = pe[s * 1024 + d];
            pep += e; pe2p = fmaf(e, e, pe2p); psp = fmaf(qlw[d], e, psp);
            const float* wr = Wp + (size_t)d * 16;
            #pragma unroll
            for (int j = 0; j < 16; ++j) pwp[j] = fmaf(wr[j], e, pwp[j]);
        }
        #pragma unroll
        for (int j = 0; j < 16; ++j) pwbuf[t * 16 + j] = pwp[j];
        psbuf[t] = psp;
        float pes = block_sum(pep, red);     // barriers make pwbuf/psbuf visible
        float pe2s = block_sum(pe2p, red);
        if (t < 16) {
            float a = 0.f;
            for (int k = 0; k < 256; ++k) a += pwbuf[k * 16 + t];
            pwt[s * 16 + t] = a;
            float b = 0.f;
            #pragma unroll
            for (int k = 0; k < 16; ++k) b += psbuf[t * 16 + k];
            pesum[s * 16 + t] = b;
        }
        if (t == 0) { pe2t[s] = pe2s; pemean[s] = pes * (1.f / 1024.f); }
    } else if (blk == 50) {
        int j = t >> 4, k = t & 15;
        float a = 0.f;
        for (int d = 0; d < 1024; ++d)
            a = fmaf(Wp[(size_t)d * 16 + j], Wp[(size_t)d * 16 + k], a);
        Gt[j * 16 + k] = a;
        if (t < 16) {
            float ua = 0.f;
            for (int d = 0; d < 1024; ++d) ua += Wp[(size_t)d * 16 + t];
            ut[t] = ua * (1.f / 1024.f);
        }
    } else {
        int h = t >> 4, j = t & 15;
        float a = 0.f;
        for (int dl = 0; dl < 64; ++dl) {
            int d = h * 64 + dl;
            a = fmaf(qlw[d], Wp[(size_t)d * 16 + j], a);
        }
        gt[h * 16 + j] = a;
    }
}

// ---------------------------------------------------------------------------
// Fused embed+attention. One wave per batch (4 waves/block, grid 256).
// Phase A (lane=s): patch stats + 16 head scores from 16-dim algebra.
// Phase B: softmax per head (4 lanes/head). Phase C: wpatch_h, wmu_h.
// Phase D: c[d] (lane owns 16 d). Phase E: A0 = Wv c + bv (lane owns 16 e).
// ---------------------------------------------------------------------------
__global__ __launch_bounds__(256) void k_fused(
    const float* __restrict__ x, const float* __restrict__ pe,
    const float* __restrict__ Wp,
    const float* __restrict__ ln1w, const float* __restrict__ ln1b,
    const float* __restrict__ Wv, const float* __restrict__ bv,
    const float* __restrict__ n0g, const float* __restrict__ score0,
    const float* __restrict__ kap, const float* __restrict__ bet,
    const float* __restrict__ Gt, const float* __restrict__ ut,
    const float* __restrict__ gt,
    const float* __restrict__ pwt, const float* __restrict__ pe2t,
    const float* __restrict__ pemean, const float* __restrict__ pesum,
    float* __restrict__ A0)
{
    __shared__ float Gs[256], gs[256];
    __shared__ float us[16], kaps[16], bets[16], s0s[16];
    __shared__ int   prc[50];
    __shared__ float xs[4][800];
    __shared__ float mus[4][52], rss[4][52];
    __shared__ float sc[4][16][52];
    __shared__ float wpat[4][16][17];
    __shared__ float wmus[4][16];
    __shared__ float csh[4][16][68];

    int t = threadIdx.x, w = t >> 6, lane = t & 63;
    int b = blockIdx.x * 4 + w;

    Gs[t] = Gt[t];
    gs[t] = gt[t];
    if (t < 16) { us[t] = ut[t]; kaps[t] = kap[t]; bets[t] = bet[t]; s0s[t] = score0[t]; }
    if (t >= 1 && t < 50) prc[t] = ((t - 1) / 7) * 112 + ((t - 1) % 7) * 4;
    for (int i = lane; i < 784; i += 64) xs[w][i] = x[b * 784 + i];
    __syncthreads();

    // ---- Phase A: per-row stats + scores (lane = s) ----
    {
        int s = lane;
        if (s >= 1 && s < 50) {
            float p[16];
            int off = prc[s];
            #pragma unroll
            for (int j = 0; j < 16; ++j) p[j] = xs[w][off + (j >> 2) * 28 + (j & 3)];
            float mu = pemean[s];
            #pragma unroll
            for (int j = 0; j < 16; ++j) mu = fmaf(us[j], p[j], mu);
            float ssq = pe2t[s];
            #pragma unroll
            for (int j = 0; j < 16; ++j) {
                float gpj = 0.f;
                #pragma unroll
                for (int k = 0; k < 16; ++k) gpj = fmaf(Gs[j * 16 + k], p[k], gpj);
                ssq = fmaf(p[j], gpj, ssq);
            }
            const float* pwr = pwt + s * 16;
            #pragma unroll
            for (int j = 0; j < 16; ++j) ssq = fmaf(2.f * p[j], pwr[j], ssq);
            float var = ssq * (1.f / 1024.f) - mu * mu;
            float rsv = rsqrtf(var + EPS);
            mus[w][s] = mu; rss[w][s] = rsv;
            const float* pss = pesum + s * 16;
            #pragma unroll
            for (int h = 0; h < 16; ++h) {
                float gp = 0.f;
                #pragma unroll
                for (int j = 0; j < 16; ++j) gp = fmaf(gs[h * 16 + j], p[j], gp);
                sc[w][h][s] = rsv * (gp + pss[h] - mu * kaps[h]) + bets[h];
            }
        } else if (s == 50) {
            #pragma unroll
            for (int h = 0; h < 16; ++h) sc[w][h][0] = s0s[h];
        }
    }
    __syncthreads();

    // ---- Phase B: softmax over 50 per head (4 lanes per head) ----
    int h = lane & 15, q = lane >> 4;
    {
        int sb = q * 13, se = (sb + 13 < 50) ? sb + 13 : 50;
        float mx = -1e30f;
        for (int ss = sb; ss < se; ++ss) mx = fmaxf(mx, sc[w][h][ss]);
        mx = fmaxf(mx, __shfl_xor(mx, 16, 64));
        mx = fmaxf(mx, __shfl_xor(mx, 32, 64));
        float sm = 0.f;
        for (int ss = sb; ss < se; ++ss) {
            float e = expf(sc[w][h][ss] - mx);
            sc[w][h][ss] = e;
            sm += e;
        }
        sm += __shfl_xor(sm, 16, 64);
        sm += __shfl_xor(sm, 32, 64);
        float inv = 1.f / sm;
        for (int ss = sb; ss < se; ++ss) sc[w][h][ss] *= inv;
    }
    __syncthreads();

    // ---- Phase C: wpatch_h[16], wmu_h ----
    {
        int sb = q * 13, se = (sb + 13 < 50) ? sb + 13 : 50;
        int s0c = (q == 0) ? 1 : sb;
        float acc[16], amu = 0.f;
        #pragma unroll
        for (int j = 0; j < 16; ++j) acc[j] = 0.f;
        for (int ss = s0c; ss < se; ++ss) {
            float wgt = sc[w][h][ss] * rss[w][ss];
            int off = prc[ss];
            #pragma unroll
            for (int j = 0; j < 16; ++j)
                acc[j] = fmaf(wgt, xs[w][off + (j >> 2) * 28 + (j & 3)], acc[j]);
            amu = fmaf(wgt, mus[w][ss], amu);
        }
        #pragma unroll
        for (int j = 0; j < 16; ++j) {
            acc[j] += __shfl_xor(acc[j], 16, 64);
            acc[j] += __shfl_xor(acc[j], 32, 64);
        }
        amu += __shfl_xor(amu, 16, 64);
        amu += __shfl_xor(amu, 32, 64);
        if (q == 0) {
            #pragma unroll
            for (int j = 0; j < 16; ++j) wpat[w][h][j] = acc[j];
            wmus[w][h] = amu;
        }
    }
    __syncthreads();

    // ---- Phase D: context c (lane owns d = 16*lane .. +15) ----
    {
        int d0 = lane * 16;
        int hh = lane >> 2;
        int dl0 = (lane & 3) * 16;
        float p0 = sc[w][hh][0];
        float wpe[16];
        #pragma unroll
        for (int i = 0; i < 16; ++i) wpe[i] = 0.f;
        for (int ss = 1; ss < 50; ++ss) {
            float wgt = sc[w][hh][ss] * rss[w][ss];
            const float4* per = (const float4*)(pe + ss * 1024 + d0);
            #pragma unroll
            for (int i4 = 0; i4 < 4; ++i4) {
                float4 v = per[i4];
                wpe[i4 * 4 + 0] = fmaf(wgt, v.x, wpe[i4 * 4 + 0]);
                wpe[i4 * 4 + 1] = fmaf(wgt, v.y, wpe[i4 * 4 + 1]);
                wpe[i4 * 4 + 2] = fmaf(wgt, v.z, wpe[i4 * 4 + 2]);
                wpe[i4 * 4 + 3] = fmaf(wgt, v.w, wpe[i4 * 4 + 3]);
            }
        }
        float wmu = wmus[w][hh];
        #pragma unroll
        for (int i = 0; i < 16; ++i) {
            int d = d0 + i;
            const float* wr = Wp + (size_t)d * 16;
            float wp_ = 0.f;
            #pragma unroll
            for (int j = 0; j < 16; ++j) wp_ = fmaf(wr[j], wpat[w][hh][j], wp_);
            float ci = p0 * n0g[d] + ln1w[d] * (wp_ + wpe[i] - wmu)
                     + ln1b[d] * (1.f - p0);
            csh[w][hh][dl0 + i] = ci;
        }
    }
    __syncthreads();

    // ---- Phase E: A0 = blockdiag(Wv) c + bv (lane owns e = 16*lane .. +15) ----
    {
        int e0 = lane * 16;
        int hh = lane >> 2;
        int el0 = (lane & 3) * 16;
        #pragma unroll
        for (int i = 0; i < 16; ++i) {
            int e = e0 + i;
            const float* wr = Wv + ((size_t)hh << 12) + (el0 + i) * 64;
            float acc = bv[e];
            #pragma unroll 16
            for (int dd = 0; dd < 64; ++dd)
                acc = fmaf(wr[dd], csh[w][hh][dd], acc);
            A0[(size_t)b * 1024 + e] = acc;
        }
    }
}

// ---------------------------------------------------------------------------
// C1: t = tok0c + A0 (residual); tok0[b]=t; LN2 -> n2. One block per b.
// ---------------------------------------------------------------------------
__global__ __launch_bounds__(256) void k_c1(
    const float* __restrict__ tok0c, const float* __restrict__ A0,
    const float* __restrict__ w2, const float* __restrict__ b2,
    float* __restrict__ tok0, float* __restrict__ n2)
{
    int b = blockIdx.x, tid = threadIdx.x;
    __shared__ float red[8];
    float t[4];
    #pragma unroll
    for (int i = 0; i < 4; ++i) {
        int d = tid + (i << 8);
        t[i] = tok0c[d] + A0[(size_t)b * 1024 + d];
    }
    float sum = block_sum(t[0] + t[1] + t[2] + t[3], red);
    float mu = sum * (1.f / 1024.f);
    float d2 = 0.f;
    #pragma unroll
    for (int i = 0; i < 4; ++i) { float dv = t[i] - mu; d2 = fmaf(dv, dv, d2); }
    float var = block_sum(d2, red) * (1.f / 1024.f);
    float rstd = rsqrtf(var + EPS);
    #pragma unroll
    for (int i = 0; i < 4; ++i) {
        int d = tid + (i << 8);
        tok0[(size_t)b * 1024 + d] = t[i];
        n2[(size_t)b * 1024 + d] = (t[i] - mu) * rstd * w2[d] + b2[d];
    }
}

// ---------------------------------------------------------------------------
// Split-K LDS-tiled f32 GEMM (round-9 measured). Grid (N/64, 16, 8).
// ---------------------------------------------------------------------------
__global__ __launch_bounds__(256) void k_gemm_sk(
    const float* __restrict__ A, const float* __restrict__ Bw,
    float* __restrict__ Cp, int N, int K)
{
    __shared__ __align__(16) float As[32 * 68];
    __shared__ __align__(16) float Bs[32 * 68];
    int n0 = blockIdx.x * 64, m0 = blockIdx.y * 64;
    int kz = blockIdx.z;
    int tid = threadIdx.x;
    int mt = (tid & 15) * 4, nt = (tid >> 4) * 4;
    float acc[4][4] = {{0.f}};

    int kbeg = kz * 128;
    for (int k0 = kbeg; k0 < kbeg + 128; k0 += 32) {
        for (int idx = tid; idx < 64 * 32; idx += 256) {
            int kk = idx & 31, m = idx >> 5;
            As[kk * 68 + m] = A[(size_t)(m0 + m) * K + k0 + kk];
            float bvv = (n0 + m < N) ? Bw[(size_t)(n0 + m) * K + k0 + kk] : 0.f;
            Bs[kk * 68 + m] = bvv;
        }
        __syncthreads();
        #pragma unroll 8
        for (int kk = 0; kk < 32; ++kk) {
            float4 av = *(const float4*)&As[kk * 68 + mt];
            float4 bv = *(const float4*)&Bs[kk * 68 + nt];
            acc[0][0] = fmaf(av.x, bv.x, acc[0][0]);
            acc[0][1] = fmaf(av.x, bv.y, acc[0][1]);
            acc[0][2] = fmaf(av.x, bv.z, acc[0][2]);
            acc[0][3] = fmaf(av.x, bv.w, acc[0][3]);
            acc[1][0] = fmaf(av.y, bv.x, acc[1][0]);
            acc[1][1] = fmaf(av.y, bv.y, acc[1][1]);
            acc[1][2] = fmaf(av.y, bv.z, acc[1][2]);
            acc[1][3] = fmaf(av.y, bv.w, acc[1][3]);
            acc[2][0] = fmaf(av.z, bv.x, acc[2][0]);
            acc[2][1] = fmaf(av.z, bv.y, acc[2][1]);
            acc[2][2] = fmaf(av.z, bv.z, acc[2][2]);
            acc[2][3] = fmaf(av.z, bv.w, acc[2][3]);
            acc[3][0] = fmaf(av.w, bv.x, acc[3][0]);
            acc[3][1] = fmaf(av.w, bv.y, acc[3][1]);
            acc[3][2] = fmaf(av.w, bv.z, acc[3][2]);
            acc[3][3] = fmaf(av.w, bv.w, acc[3][3]);
        }
        __syncthreads();
    }

    float* cpb = Cp + (size_t)kz * ((size_t)1024 * N);
    #pragma unroll
    for (int i = 0; i < 4; ++i) {
        int r = m0 + mt + i;
        #pragma unroll
        for (int j = 0; j < 4; ++j) {
            int c = n0 + nt + j;
            if (c < N) cpb[(size_t)r * N + c] = acc[i][j];
        }
    }
}

// ---------------------------------------------------------------------------
// Reduce split-K partials: C = sum Cp + bias + (res?).
// ---------------------------------------------------------------------------
__global__ __launch_bounds__(256) void k_reduce(
    const float* __restrict__ Cp, const float* __restrict__ bias,
    const float* __restrict__ res, float* __restrict__ C, int N)
{
    const int N4 = N >> 2;
    int e4 = blockIdx.x * 256 + threadIdx.x;
    if (e4 >= 1024 * N4) return;
    int r = e4 / N4;
    int c = (e4 - r * N4) << 2;
    size_t off = (size_t)r * N + c;
    const size_t slice = (size_t)1024 * N;
    float4 s = make_float4(0.f, 0.f, 0.f, 0.f);
    #pragma unroll
    for (int kz = 0; kz < 8; ++kz) {
        float4 v = *(const float4*)(Cp + kz * slice + off);
        s.x += v.x; s.y += v.y; s.z += v.z; s.w += v.w;
    }
    float4 bb = *(const float4*)(bias + c);
    s.x += bb.x; s.y += bb.y; s.z += bb.z; s.w += bb.w;
    if (res) {
        float4 rv = *(const float4*)(res + off);
        s.x += rv.x; s.y += rv.y; s.z += rv.z; s.w += rv.w;
    }
    *(float4*)(C + off) = s;
}

// ---------------------------------------------------------------------------
// Row softmax over 1000 logits -> d_out
// ---------------------------------------------------------------------------
__global__ __launch_bounds__(256) void k_softmax(
    const float* __restrict__ logits, float* __restrict__ out)
{
    int b = blockIdx.x, tid = threadIdx.x;
    __shared__ float red[8];
    float v[4];
    #pragma unroll
    for (int i = 0; i < 4; ++i) {
        int idx = tid + (i << 8);
        v[i] = (idx < 1000) ? logits[(size_t)b * 1000 + idx] : -INFINITY;
    }
    float mx = fmaxf(fmaxf(v[0], v[1]), fmaxf(v[2], v[3]));
    mx = block_max(mx, red);
    float e[4]; float s = 0.f;
    #pragma unroll
    for (int i = 0; i < 4; ++i) {
        int idx = tid + (i << 8);
        e[i] = (idx < 1000) ? expf(v[i] - mx) : 0.f;
        s += e[i];
    }
    s = block_sum(s, red);
    float inv = 1.f / s;
    #pragma unroll
    for (int i = 0; i < 4; ++i) {
        int idx = tid + (i << 8);
        if (idx < 1000) out[(size_t)b * 1000 + idx] = e[i] * inv;
    }
}

// ---------------------------------------------------------------------------
extern "C" void kernel_launch(void* const* d_in, const int* in_sizes, int n_in,
                              void* d_out, int out_size, void* d_ws, size_t ws_size,
                              hipStream_t stream)
{
    const float* x    = (const float*)d_in[0];
    const float* cls  = (const float*)d_in[1];
    const float* Wp   = (const float*)d_in[2];
    const float* ln1w = (const float*)d_in[3];
    const float* ln1b = (const float*)d_in[4];
    const float* Wq   = (const float*)d_in[5];
    const float* bq   = (const float*)d_in[6];
    const float* Wk   = (const float*)d_in[7];
    const float* bk   = (const float*)d_in[8];
    const float* Wv   = (const float*)d_in[9];
    const float* bv   = (const float*)d_in[10];
    const float* ln2w = (const float*)d_in[11];
    const float* ln2b = (const float*)d_in[12];
    const float* Wm   = (const float*)d_in[13];
    const float* bm   = (const float*)d_in[14];
    const float* Wh   = (const float*)d_in[15];
    const float* bh   = (const float*)d_in[16];
    float* out = (float*)d_out;
    (void)bk;   // q0.bk softmax-invariant

    char* ws = (char*)d_ws;
    size_t off = 0;
    auto alloc = [&](size_t nfloats) -> float* {
        float* p = (float*)(ws + off);
        off += ((nfloats * 4 + 255) & ~(size_t)255);
        return p;
    };
    float* pe     = alloc(50 * 1024);
    float* tok0c  = alloc(1024);
    float* n0g    = alloc(1024);
    float* qlw    = alloc(1024);
    float* score0 = alloc(16);
    float* kap    = alloc(16);
    float* bet    = alloc(16);
    float* Gt     = alloc(256);
    float* ut     = alloc(16);
    float* gt     = alloc(256);
    float* pwt    = alloc(50 * 16);
    float* pe2t   = alloc(50);
    float* pemean = alloc(50);
    float* pesum  = alloc(50 * 16);
    float* A0     = alloc((size_t)1024 * 1024);
    float* tok0   = alloc((size_t)1024 * 1024);
    float* n2     = alloc((size_t)1024 * 1024);
    float* t2     = alloc((size_t)1024 * 1024);
    float* logits = alloc((size_t)1024 * 1000);
    float* Cp     = alloc((size_t)8 * 1024 * 1024);

    k_pe<<<50, 256, 0, stream>>>(pe);
    k_prep_a<<<1, 256, 0, stream>>>(cls, pe, ln1w, ln1b, Wq, bq, Wk,
                                    tok0c, n0g, qlw, score0, kap, bet);
    k_prep_b<<<52, 256, 0, stream>>>(pe, Wp, qlw, pwt, pe2t, pemean, pesum,
                                     Gt, ut, gt);
    k_fused<<<256, 256, 0, stream>>>(x, pe, Wp, ln1w, ln1b, Wv, bv,
                                     n0g, score0, kap, bet, Gt, ut, gt,
                                     pwt, pe2t, pemean, pesum, A0);

    k_c1<<<1024, 256, 0, stream>>>(tok0c, A0, ln2w, ln2b, tok0, n2);

    // MLP GEMM (row 0): t2 = tok0 + n2 @ Wm^T + bm
    k_gemm_sk<<<dim3(16, 16, 8), 256, 0, stream>>>(n2, Wm, Cp, 1024, 1024);
    k_reduce<<<1024, 256, 0, stream>>>(Cp, bm, tok0, t2, 1024);

    // Head GEMM: logits = t2 @ Wh^T + bh
    k_gemm_sk<<<dim3(16, 16, 8), 256, 0, stream>>>(t2, Wh, Cp, 1000, 1024);
    k_reduce<<<1000, 256, 0, stream>>>(Cp, bh, nullptr, logits, 1000);

    k_softmax<<<1024, 256, 0, stream>>>(logits, out);
}